// Round 10
// baseline (122.530 us; speedup 1.0000x reference)
//
#include <hip/hip_runtime.h>
#include <hip/hip_bf16.h>

#define NN 65536   // N*N rows
#define DD 128
#define NH 4
#define HDIM 32

typedef __bf16 bf16_t;
typedef __bf16 bf16x8 __attribute__((ext_vector_type(8)));
typedef __bf16 bf16x4 __attribute__((ext_vector_type(4)));
typedef __bf16 bf16x2 __attribute__((ext_vector_type(2)));
typedef float f32x4 __attribute__((ext_vector_type(4)));
typedef float f32x16 __attribute__((ext_vector_type(16)));
typedef unsigned int u32;
typedef unsigned int u32x4 __attribute__((ext_vector_type(4)));

__device__ inline u32 pk2(float a, float b) {
    bf16x2 t;
    t[0] = (bf16_t)a;
    t[1] = (bf16_t)b;
    return __builtin_bit_cast(u32, t);
}
__device__ inline bf16x8 frag4(u32 a, u32 b, u32 c, u32 d) {
    u32x4 t = {a, b, c, d};
    return __builtin_bit_cast(bf16x8, t);
}
__device__ inline bf16x8 cat44(bf16x4 a, bf16x4 b) {
    bf16x8 r;
#pragma unroll
    for (int j = 0; j < 4; j++) { r[j] = a[j]; r[4 + j] = b[j]; }
    return r;
}
// VERIFIED (R2-R6): pack C-layout (col=lane&31, c=(r&3)+8*(r>>2)+4*hi) into two
// contiguous frags via shfl. f0 = lane's c[hi*8..+8), f1 = c[16+hi*8..+8).
__device__ inline void packX(const f32x16& s, bool lo, bf16x8& f0, bf16x8& f1) {
    u32 wv[8];
#pragma unroll
    for (int g = 0; g < 4; g++) {
        wv[2 * g] = pk2(s[4 * g], s[4 * g + 1]);
        wv[2 * g + 1] = pk2(s[4 * g + 2], s[4 * g + 3]);
    }
    u32 p0 = __shfl_xor(wv[0], 32), p1 = __shfl_xor(wv[1], 32);
    u32 p2 = __shfl_xor(wv[2], 32), p3 = __shfl_xor(wv[3], 32);
    u32 p4 = __shfl_xor(wv[4], 32), p5 = __shfl_xor(wv[5], 32);
    u32 p6 = __shfl_xor(wv[6], 32), p7 = __shfl_xor(wv[7], 32);
    f0 = frag4(lo ? wv[0] : p2, lo ? wv[1] : p3, lo ? p0 : wv[2], lo ? p1 : wv[3]);
    f1 = frag4(lo ? wv[4] : p6, lo ? wv[5] : p7, lo ? p4 : wv[6], lo ? p5 : wv[7]);
}

// ---------------- weight transpose + bf16 cast: Wt[m][out][in] ----------------
__global__ __launch_bounds__(128) void convw_kernel(const float* __restrict__ w0,
                                                    const float* __restrict__ w1,
                                                    const float* __restrict__ w2,
                                                    const float* __restrict__ w3,
                                                    const float* __restrict__ w4,
                                                    bf16_t* __restrict__ wt) {
    int m = blockIdx.x >> 7;
    int o = blockIdx.x & 127;
    int d = threadIdx.x;
    const float* W = (m == 0) ? w0 : (m == 1) ? w1 : (m == 2) ? w2 : (m == 3) ? w3 : w4;
    wt[(m * 128 + o) * 128 + d] = (bf16_t)W[d * 128 + o];
}

// ---------------- LayerNorm + fused triangle bias (natural order) ----------------
__global__ __launch_bounds__(256) void ln_kernel(const float* __restrict__ x,
                                                 const float* __restrict__ lw,
                                                 const float* __restrict__ lb,
                                                 const float* __restrict__ Wb,
                                                 bf16_t* __restrict__ z,
                                                 float* __restrict__ bias3) {
    __shared__ float bias_s[4][8];
    int t = threadIdx.x;
    int wv = t >> 6, lane = t & 63;
    int sub = lane >> 5, l32 = lane & 31;
    int rowbase = blockIdx.x * 8;
    int row = rowbase + wv * 2 + sub;
    int d0 = l32 * 4;
    f32x4 v = *reinterpret_cast<const f32x4*>(&x[row * 128 + d0]);
    float s1 = v[0] + v[1] + v[2] + v[3];
    float s2 = v[0] * v[0] + v[1] * v[1] + v[2] * v[2] + v[3] * v[3];
#pragma unroll
    for (int m = 1; m < 32; m <<= 1) {
        s1 += __shfl_xor(s1, m);
        s2 += __shfl_xor(s2, m);
    }
    float mu = s1 * (1.0f / 128.0f);
    float var = s2 * (1.0f / 128.0f) - mu * mu;
    float rs = rsqrtf(var + 1e-5f);
    f32x4 lwv = *reinterpret_cast<const f32x4*>(&lw[d0]);
    f32x4 lbv = *reinterpret_cast<const f32x4*>(&lb[d0]);
    float zv[4];
    bf16x4 pk;
#pragma unroll
    for (int j = 0; j < 4; j++) {
        zv[j] = (v[j] - mu) * rs * lwv[j] + lbv[j];
        pk[j] = (bf16_t)zv[j];
    }
    *reinterpret_cast<bf16x4*>(&z[row * 128 + d0]) = pk;
    f32x4 pb = {0.f, 0.f, 0.f, 0.f};
#pragma unroll
    for (int j = 0; j < 4; j++) {
        f32x4 wbj = *reinterpret_cast<const f32x4*>(&Wb[(d0 + j) * 4]);
#pragma unroll
        for (int hh = 0; hh < 4; hh++) pb[hh] += zv[j] * wbj[hh];
    }
#pragma unroll
    for (int m = 1; m < 32; m <<= 1) {
#pragma unroll
        for (int hh = 0; hh < 4; hh++) pb[hh] += __shfl_xor(pb[hh], m);
    }
    if (l32 == 0) {
#pragma unroll
        for (int hh = 0; hh < 4; hh++)
            bias_s[hh][wv * 2 + sub] = pb[hh] * 1.4426950408889634f;
    }
    __syncthreads();
    if (t < 32) {
        int hh = t >> 3, rl = t & 7;
        bias3[hh * NN + rowbase + rl] = bias_s[hh][rl];
    }
}

// ---------------- bias transpose: bias2[h][k][q] = bias3[h][q*256+k] ----------------
__global__ __launch_bounds__(256) void biastr_kernel(const float* __restrict__ bias3,
                                                     float* __restrict__ bias2) {
    __shared__ float T[64][68];
    int t = threadIdx.x;
    int h = blockIdx.x >> 4;
    int q0 = ((blockIdx.x >> 2) & 3) * 64, k0 = (blockIdx.x & 3) * 64;
#pragma unroll
    for (int i = 0; i < 4; i++) {
        int id = i * 256 + t;
        int r = id >> 4, cb = id & 15;
        f32x4 val = *reinterpret_cast<const f32x4*>(&bias3[h * NN + (q0 + r) * 256 + k0 + cb * 4]);
        *reinterpret_cast<f32x4*>(&T[r][cb * 4]) = val;
    }
    __syncthreads();
#pragma unroll
    for (int i = 0; i < 4; i++) {
        int id = i * 256 + t;
        int kr = id >> 4, qb = id & 15;
        f32x4 o;
#pragma unroll
        for (int j = 0; j < 4; j++) o[j] = T[qb * 4 + j][kr];
        *reinterpret_cast<f32x4*>(&bias2[h * NN + (k0 + kr) * 256 + q0 + qb * 4]) = o;
    }
}

// ---------- fused G + QKV projection + flash attention per (b,h) ----------
// z [row][128]; wt[m][out][in]; bias2 [h][key][q]; om2/gm2 head-major [h][row][32]
// Projection split into {K,V} -> barrier -> {Q,G}: max 4 f32x16 accumulators
// live at once (64 regs) so (256,4) fits without spill (R8: 6 acc + (256,4)
// spilled ~60MB scratch; R9: (256,3) no spill but only 25% occupancy).
__global__ __launch_bounds__(256, 4) void fat_kernel(const bf16_t* __restrict__ z,
                                                     const bf16_t* __restrict__ wt,
                                                     const float* __restrict__ bias2,
                                                     bf16_t* __restrict__ om2,
                                                     bf16_t* __restrict__ gm2) {
    __shared__ bf16_t Kh[256][44];   // [key][c] padded -> conflict-free b128
    __shared__ bf16_t Vt[32][268];   // [c][key] padded -> 2-way b64 (free)
    int t = threadIdx.x;
    int b = blockIdx.x >> 2, h = blockIdx.x & 3;
    int w = t >> 6, lane = t & 63;
    int rsel = lane & 31, hi = lane >> 5;
    int hi8 = hi * 8, hi4 = hi * 4;
    bool lo = (hi == 0);
    const float SCL2 = 0.17677669529663687f * 1.4426950408889634f;  // scale * log2(e)
    const bf16_t* zr0 = z + (size_t)(b * 256 + w * 64 + rsel) * 128;
    const bf16_t* zr1 = zr0 + 32 * 128;

    // ---- Phase 1: K,V projection (swapped MFMA, C[c,row]) -> LDS ----
    {
        const bf16_t* wkr = wt + (size_t)(1 * 128 + h * 32 + rsel) * 128;
        const bf16_t* wvr = wt + (size_t)(2 * 128 + h * 32 + rsel) * 128;
        f32x16 ak0, ak1, av0, av1;
#pragma unroll
        for (int i = 0; i < 16; i++) { ak0[i] = 0.f; ak1[i] = 0.f; av0[i] = 0.f; av1[i] = 0.f; }
#pragma unroll
        for (int ks = 0; ks < 8; ks++) {
            int d = ks * 16 + hi8;
            bf16x8 zb0 = *reinterpret_cast<const bf16x8*>(zr0 + d);
            bf16x8 zb1 = *reinterpret_cast<const bf16x8*>(zr1 + d);
            bf16x8 ak = *reinterpret_cast<const bf16x8*>(wkr + d);
            bf16x8 av = *reinterpret_cast<const bf16x8*>(wvr + d);
            ak0 = __builtin_amdgcn_mfma_f32_32x32x16_bf16(ak, zb0, ak0, 0, 0, 0);
            ak1 = __builtin_amdgcn_mfma_f32_32x32x16_bf16(ak, zb1, ak1, 0, 0, 0);
            av0 = __builtin_amdgcn_mfma_f32_32x32x16_bf16(av, zb0, av0, 0, 0, 0);
            av1 = __builtin_amdgcn_mfma_f32_32x32x16_bf16(av, zb1, av1, 0, 0, 0);
        }
        int key0 = w * 64 + rsel;
        bf16x8 f0, f1;
        packX(ak0, lo, f0, f1);
        *reinterpret_cast<bf16x8*>(&Kh[key0][hi8]) = f0;
        *reinterpret_cast<bf16x8*>(&Kh[key0][16 + hi8]) = f1;
        packX(ak1, lo, f0, f1);
        *reinterpret_cast<bf16x8*>(&Kh[key0 + 32][hi8]) = f0;
        *reinterpret_cast<bf16x8*>(&Kh[key0 + 32][16 + hi8]) = f1;
#pragma unroll
        for (int r = 0; r < 16; r++) {
            int c = (r & 3) + 8 * (r >> 2) + hi4;
            Vt[c][key0] = (bf16_t)av0[r];
            Vt[c][key0 + 32] = (bf16_t)av1[r];
        }
    }
    __syncthreads();   // K/V visible to all waves; Q/G comes after (off barrier path)

    // ---- Phase 2: Q,G projection ----
    bf16x8 qf[2][2];
    {
        const bf16_t* wqr = wt + (size_t)(0 * 128 + h * 32 + rsel) * 128;
        const bf16_t* wgr = wt + (size_t)(3 * 128 + h * 32 + rsel) * 128;
        f32x16 aq0, aq1, ag0, ag1;
#pragma unroll
        for (int i = 0; i < 16; i++) { aq0[i] = 0.f; aq1[i] = 0.f; ag0[i] = 0.f; ag1[i] = 0.f; }
#pragma unroll
        for (int ks = 0; ks < 8; ks++) {
            int d = ks * 16 + hi8;
            bf16x8 zb0 = *reinterpret_cast<const bf16x8*>(zr0 + d);
            bf16x8 zb1 = *reinterpret_cast<const bf16x8*>(zr1 + d);
            bf16x8 aq = *reinterpret_cast<const bf16x8*>(wqr + d);
            bf16x8 ag = *reinterpret_cast<const bf16x8*>(wgr + d);
            aq0 = __builtin_amdgcn_mfma_f32_32x32x16_bf16(aq, zb0, aq0, 0, 0, 0);
            aq1 = __builtin_amdgcn_mfma_f32_32x32x16_bf16(aq, zb1, aq1, 0, 0, 0);
            ag0 = __builtin_amdgcn_mfma_f32_32x32x16_bf16(ag, zb0, ag0, 0, 0, 0);
            ag1 = __builtin_amdgcn_mfma_f32_32x32x16_bf16(ag, zb1, ag1, 0, 0, 0);
        }
#pragma unroll
        for (int i = 0; i < 16; i++) {
            ag0[i] = 1.0f / (1.0f + __expf(-ag0[i]));
            ag1[i] = 1.0f / (1.0f + __expf(-ag1[i]));
        }
        bf16x8 g0, g1;
        bf16_t* grow = gm2 + ((size_t)h * NN + b * 256 + w * 64 + rsel) * 32;
        packX(ag0, lo, g0, g1);
        *reinterpret_cast<bf16x8*>(grow + hi8) = g0;
        *reinterpret_cast<bf16x8*>(grow + 16 + hi8) = g1;
        packX(ag1, lo, g0, g1);
        *reinterpret_cast<bf16x8*>(grow + 32 * 32 + hi8) = g0;
        *reinterpret_cast<bf16x8*>(grow + 32 * 32 + 16 + hi8) = g1;
        packX(aq0, lo, qf[0][0], qf[0][1]);
        packX(aq1, lo, qf[1][0], qf[1][1]);
    }

    // ---- flash attention ----
#pragma unroll
    for (int qt = 0; qt < 2; qt++) {
        int qpos = w * 64 + qt * 32 + rsel;
        bf16x8 qf0 = qf[qt][0];
        bf16x8 qf1 = qf[qt][1];
        const float* bq = bias2 + (size_t)h * NN + qpos;  // + key*256

        f32x16 of;
#pragma unroll
        for (int i = 0; i < 16; i++) of[i] = 0.f;
        float m = -1e30f, l = 0.f;

        float bv[16];
#pragma unroll
        for (int e = 0; e < 16; e++) {
            int key = 8 * (e >> 2) + hi4 + (e & 3);
            bv[e] = bq[(size_t)key * 256];
        }
#pragma unroll
        for (int kt = 0; kt < 8; kt++) {
            bf16x8 k0 = *reinterpret_cast<bf16x8*>(&Kh[kt * 32 + rsel][hi8]);
            bf16x8 k1 = *reinterpret_cast<bf16x8*>(&Kh[kt * 32 + rsel][16 + hi8]);
            f32x16 s;
#pragma unroll
            for (int i = 0; i < 16; i++) s[i] = 0.f;
            __builtin_amdgcn_s_setprio(1);
            s = __builtin_amdgcn_mfma_f32_32x32x16_bf16(k0, qf0, s, 0, 0, 0);
            s = __builtin_amdgcn_mfma_f32_32x32x16_bf16(k1, qf1, s, 0, 0, 0);
            __builtin_amdgcn_s_setprio(0);
            // prefetch next chunk's bias
            float bvn[16];
            if (kt < 7) {
#pragma unroll
                for (int e = 0; e < 16; e++) {
                    int key = (kt + 1) * 32 + 8 * (e >> 2) + hi4 + (e & 3);
                    bvn[e] = bq[(size_t)key * 256];
                }
            }
            float tm[8];
#pragma unroll
            for (int e = 0; e < 16; e++) s[e] = s[e] * SCL2 + bv[e];
#pragma unroll
            for (int e = 0; e < 8; e++) tm[e] = fmaxf(s[e], s[e + 8]);
#pragma unroll
            for (int st = 4; st >= 1; st >>= 1)
#pragma unroll
                for (int e = 0; e < st; e++) tm[e] = fmaxf(tm[e], tm[e + st]);
            float pm = fmaxf(tm[0], __shfl_xor(tm[0], 32));
            // exact defer-max: rescale only if some lane's max grew
            if (__any(pm > m)) {
                float nm = fmaxf(m, pm);
                float al = __builtin_amdgcn_exp2f(m - nm);
                m = nm;
                l *= al;
#pragma unroll
                for (int i = 0; i < 16; i++) of[i] *= al;
            }
            float ts[8];
#pragma unroll
            for (int e = 0; e < 16; e++) s[e] = __builtin_amdgcn_exp2f(s[e] - m);
#pragma unroll
            for (int e = 0; e < 8; e++) ts[e] = s[e] + s[e + 8];
#pragma unroll
            for (int st = 4; st >= 1; st >>= 1)
#pragma unroll
                for (int e = 0; e < st; e++) ts[e] += ts[e + st];
            l += ts[0];
            // P fragments in native C-layout key order (no cross-lane pack):
            // pf0 keys {4hi+0..3, 8+4hi+0..3}, pf1 keys {16+4hi+0..3, 24+4hi+0..3}
            bf16x8 pf0 = frag4(pk2(s[0], s[1]), pk2(s[2], s[3]),
                               pk2(s[4], s[5]), pk2(s[6], s[7]));
            bf16x8 pf1 = frag4(pk2(s[8], s[9]), pk2(s[10], s[11]),
                               pk2(s[12], s[13]), pk2(s[14], s[15]));
            // V fragments with the SAME key order: paired b64 reads
            bf16x8 va = cat44(*reinterpret_cast<bf16x4*>(&Vt[rsel][kt * 32 + hi4]),
                              *reinterpret_cast<bf16x4*>(&Vt[rsel][kt * 32 + 8 + hi4]));
            bf16x8 vb = cat44(*reinterpret_cast<bf16x4*>(&Vt[rsel][kt * 32 + 16 + hi4]),
                              *reinterpret_cast<bf16x4*>(&Vt[rsel][kt * 32 + 24 + hi4]));
            __builtin_amdgcn_s_setprio(1);
            of = __builtin_amdgcn_mfma_f32_32x32x16_bf16(va, pf0, of, 0, 0, 0);
            of = __builtin_amdgcn_mfma_f32_32x32x16_bf16(vb, pf1, of, 0, 0, 0);
            __builtin_amdgcn_s_setprio(0);
            if (kt < 7) {
#pragma unroll
                for (int e = 0; e < 16; e++) bv[e] = bvn[e];
            }
        }

        l += __shfl_xor(l, 32);
        float linv = 1.0f / l;
#pragma unroll
        for (int i = 0; i < 16; i++) of[i] *= linv;
        bf16x8 o0, o1;
        packX(of, lo, o0, o1);
        bf16_t* orow = om2 + ((size_t)h * NN + b * 256 + qpos) * 32;
        *reinterpret_cast<bf16x8*>(orow + hi8) = o0;
        *reinterpret_cast<bf16x8*>(orow + 16 + hi8) = o1;
    }
}

// ---------------- final: out = (o*g) @ Wo, fp32 out, LDS-staged epilogue ----------
__global__ __launch_bounds__(256) void final_kernel(const bf16_t* __restrict__ om2,
                                                    const bf16_t* __restrict__ gm2,
                                                    const bf16_t* __restrict__ wot,
                                                    float* __restrict__ out) {
    __shared__ __align__(16) char smraw[64 * 136 * 2];
    bf16_t(*As)[136] = reinterpret_cast<bf16_t(*)[136]>(smraw);
    float(*Of)[68] = reinterpret_cast<float(*)[68]>(smraw);
    int t = threadIdx.x;
    int rb = blockIdx.x;
#pragma unroll
    for (int i = 0; i < 4; i++) {
        int c = i * 256 + t;
        int r = c >> 4, off = (c & 15) * 8;
        size_t hm = ((size_t)(off >> 5) * NN + rb * 64 + r) * 32 + (off & 31);
        bf16x8 o8 = *reinterpret_cast<const bf16x8*>(&om2[hm]);
        bf16x8 g8 = *reinterpret_cast<const bf16x8*>(&gm2[hm]);
        bf16x8 p8;
#pragma unroll
        for (int e = 0; e < 8; e++) p8[e] = (bf16_t)((float)o8[e] * (float)g8[e]);
        *reinterpret_cast<bf16x8*>(&As[r][off]) = p8;
    }
    __syncthreads();
    int w = t >> 6, lane = t & 63;
    int lx = lane & 15, ly = lane >> 4;
    int m0 = (w >> 1) * 32, n0 = (w & 1) * 32;
    bf16x8 af[2][4];
#pragma unroll
    for (int mt = 0; mt < 2; mt++)
#pragma unroll
        for (int ks = 0; ks < 4; ks++)
            af[mt][ks] = *reinterpret_cast<bf16x8*>(&As[m0 + mt * 16 + lx][ks * 32 + ly * 8]);
    __syncthreads();  // As dead; Of may alias

    for (int half = 0; half < 2; half++) {
        int nc0 = half * 64;
        bf16x8 bfr[2][4];
#pragma unroll
        for (int nt = 0; nt < 2; nt++)
#pragma unroll
            for (int ks = 0; ks < 4; ks++)
                bfr[nt][ks] = *reinterpret_cast<const bf16x8*>(
                    &wot[(nc0 + n0 + nt * 16 + lx) * 128 + ks * 32 + ly * 8]);
        f32x4 acc[2][2];
#pragma unroll
        for (int mt = 0; mt < 2; mt++)
#pragma unroll
            for (int nt = 0; nt < 2; nt++) acc[mt][nt] = (f32x4){0.f, 0.f, 0.f, 0.f};
#pragma unroll
        for (int ks = 0; ks < 4; ks++)
#pragma unroll
            for (int mt = 0; mt < 2; mt++)
#pragma unroll
                for (int nt = 0; nt < 2; nt++)
                    acc[mt][nt] = __builtin_amdgcn_mfma_f32_16x16x32_bf16(af[mt][ks], bfr[nt][ks], acc[mt][nt], 0, 0, 0);
#pragma unroll
        for (int mt = 0; mt < 2; mt++)
#pragma unroll
            for (int nt = 0; nt < 2; nt++)
#pragma unroll
                for (int r = 0; r < 4; r++)
                    Of[m0 + mt * 16 + ly * 4 + r][n0 + nt * 16 + lx] = acc[mt][nt][r];
        __syncthreads();
#pragma unroll
        for (int j = 0; j < 4; j++) {
            int ch = j * 256 + t;
            int r = ch >> 4, cb = ch & 15;
            f32x4 val = *reinterpret_cast<f32x4*>(&Of[r][cb * 4]);
            *reinterpret_cast<f32x4*>(&out[(rb * 64 + r) * 128 + nc0 + cb * 4]) = val;
        }
        __syncthreads();
    }
}

extern "C" void kernel_launch(void* const* d_in, const int* in_sizes, int n_in,
                              void* d_out, int out_size, void* d_ws, size_t ws_size,
                              hipStream_t stream) {
    const float* x   = (const float*)d_in[0];
    const float* lnw = (const float*)d_in[1];
    const float* lnb = (const float*)d_in[2];
    const float* Wb  = (const float*)d_in[3];
    const float* Wq  = (const float*)d_in[4];
    const float* Wk  = (const float*)d_in[5];
    const float* Wv  = (const float*)d_in[6];
    const float* Wg  = (const float*)d_in[7];
    const float* Wo  = (const float*)d_in[8];
    float* out = (float*)d_out;

    char* ws = (char*)d_ws;
    const size_t MAT = (size_t)NN * 128 * sizeof(bf16_t);  // 16 MB
    bf16_t* z     = (bf16_t*)(ws);
    bf16_t* gmat  = (bf16_t*)(ws + MAT);                     // head-major
    bf16_t* omat  = (bf16_t*)(ws + 2 * MAT);                 // head-major
    bf16_t* wt    = (bf16_t*)(ws + 3 * MAT);                 // 5 * 128*128 bf16 = 160KB
    float*  bias3 = (float*)(ws + 3 * MAT + (1 << 20));      // 1MB
    float*  bias2 = (float*)(ws + 3 * MAT + (2 << 20));      // 1MB

    convw_kernel<<<640, 128, 0, stream>>>(Wq, Wk, Wv, Wg, Wo, wt);
    ln_kernel<<<8192, 256, 0, stream>>>(x, lnw, lnb, Wb, z, bias3);
    biastr_kernel<<<64, 256, 0, stream>>>(bias3, bias2);
    fat_kernel<<<1024, 256, 0, stream>>>(z, wt, bias2, omat, gmat);
    final_kernel<<<1024, 256, 0, stream>>>(omat, gmat, wt + 4 * 16384, out);
}

// Round 11
// 98.025 us; speedup vs baseline: 1.2500x; 1.2500x over previous
//
#include <hip/hip_runtime.h>
#include <hip/hip_bf16.h>

#define NN 65536   // N*N rows
#define DD 128
#define NH 4
#define HDIM 32

typedef __bf16 bf16_t;
typedef __bf16 bf16x8 __attribute__((ext_vector_type(8)));
typedef __bf16 bf16x4 __attribute__((ext_vector_type(4)));
typedef __bf16 bf16x2 __attribute__((ext_vector_type(2)));
typedef float f32x4 __attribute__((ext_vector_type(4)));
typedef float f32x16 __attribute__((ext_vector_type(16)));
typedef unsigned int u32;
typedef unsigned int u32x4 __attribute__((ext_vector_type(4)));

__device__ inline u32 pk2(float a, float b) {
    bf16x2 t;
    t[0] = (bf16_t)a;
    t[1] = (bf16_t)b;
    return __builtin_bit_cast(u32, t);
}
__device__ inline bf16x8 frag4(u32 a, u32 b, u32 c, u32 d) {
    u32x4 t = {a, b, c, d};
    return __builtin_bit_cast(bf16x8, t);
}
__device__ inline bf16x8 cat44(bf16x4 a, bf16x4 b) {
    bf16x8 r;
#pragma unroll
    for (int j = 0; j < 4; j++) { r[j] = a[j]; r[4 + j] = b[j]; }
    return r;
}
// VERIFIED (R2-R6): pack C-layout (col=lane&31, c=(r&3)+8*(r>>2)+4*hi) into two
// contiguous frags via shfl. f0 = lane's c[hi*8..+8), f1 = c[16+hi*8..+8).
__device__ inline void packX(const f32x16& s, bool lo, bf16x8& f0, bf16x8& f1) {
    u32 wv[8];
#pragma unroll
    for (int g = 0; g < 4; g++) {
        wv[2 * g] = pk2(s[4 * g], s[4 * g + 1]);
        wv[2 * g + 1] = pk2(s[4 * g + 2], s[4 * g + 3]);
    }
    u32 p0 = __shfl_xor(wv[0], 32), p1 = __shfl_xor(wv[1], 32);
    u32 p2 = __shfl_xor(wv[2], 32), p3 = __shfl_xor(wv[3], 32);
    u32 p4 = __shfl_xor(wv[4], 32), p5 = __shfl_xor(wv[5], 32);
    u32 p6 = __shfl_xor(wv[6], 32), p7 = __shfl_xor(wv[7], 32);
    f0 = frag4(lo ? wv[0] : p2, lo ? wv[1] : p3, lo ? p0 : wv[2], lo ? p1 : wv[3]);
    f1 = frag4(lo ? wv[4] : p6, lo ? wv[5] : p7, lo ? p4 : wv[6], lo ? p5 : wv[7]);
}

// ---------------- weight transpose + bf16 cast: Wt[m][out][in] ----------------
__global__ __launch_bounds__(128) void convw_kernel(const float* __restrict__ w0,
                                                    const float* __restrict__ w1,
                                                    const float* __restrict__ w2,
                                                    const float* __restrict__ w3,
                                                    const float* __restrict__ w4,
                                                    bf16_t* __restrict__ wt) {
    int m = blockIdx.x >> 7;
    int o = blockIdx.x & 127;
    int d = threadIdx.x;
    const float* W = (m == 0) ? w0 : (m == 1) ? w1 : (m == 2) ? w2 : (m == 3) ? w3 : w4;
    wt[(m * 128 + o) * 128 + d] = (bf16_t)W[d * 128 + o];
}

// ---------------- LayerNorm + fused triangle bias (natural order) ----------------
__global__ __launch_bounds__(256) void ln_kernel(const float* __restrict__ x,
                                                 const float* __restrict__ lw,
                                                 const float* __restrict__ lb,
                                                 const float* __restrict__ Wb,
                                                 bf16_t* __restrict__ z,
                                                 float* __restrict__ bias3) {
    __shared__ float bias_s[4][8];
    int t = threadIdx.x;
    int wv = t >> 6, lane = t & 63;
    int sub = lane >> 5, l32 = lane & 31;
    int rowbase = blockIdx.x * 8;
    int row = rowbase + wv * 2 + sub;
    int d0 = l32 * 4;
    f32x4 v = *reinterpret_cast<const f32x4*>(&x[row * 128 + d0]);
    float s1 = v[0] + v[1] + v[2] + v[3];
    float s2 = v[0] * v[0] + v[1] * v[1] + v[2] * v[2] + v[3] * v[3];
#pragma unroll
    for (int m = 1; m < 32; m <<= 1) {
        s1 += __shfl_xor(s1, m);
        s2 += __shfl_xor(s2, m);
    }
    float mu = s1 * (1.0f / 128.0f);
    float var = s2 * (1.0f / 128.0f) - mu * mu;
    float rs = rsqrtf(var + 1e-5f);
    f32x4 lwv = *reinterpret_cast<const f32x4*>(&lw[d0]);
    f32x4 lbv = *reinterpret_cast<const f32x4*>(&lb[d0]);
    float zv[4];
    bf16x4 pk;
#pragma unroll
    for (int j = 0; j < 4; j++) {
        zv[j] = (v[j] - mu) * rs * lwv[j] + lbv[j];
        pk[j] = (bf16_t)zv[j];
    }
    *reinterpret_cast<bf16x4*>(&z[row * 128 + d0]) = pk;
    f32x4 pb = {0.f, 0.f, 0.f, 0.f};
#pragma unroll
    for (int j = 0; j < 4; j++) {
        f32x4 wbj = *reinterpret_cast<const f32x4*>(&Wb[(d0 + j) * 4]);
#pragma unroll
        for (int hh = 0; hh < 4; hh++) pb[hh] += zv[j] * wbj[hh];
    }
#pragma unroll
    for (int m = 1; m < 32; m <<= 1) {
#pragma unroll
        for (int hh = 0; hh < 4; hh++) pb[hh] += __shfl_xor(pb[hh], m);
    }
    if (l32 == 0) {
#pragma unroll
        for (int hh = 0; hh < 4; hh++)
            bias_s[hh][wv * 2 + sub] = pb[hh] * 1.4426950408889634f;
    }
    __syncthreads();
    if (t < 32) {
        int hh = t >> 3, rl = t & 7;
        bias3[hh * NN + rowbase + rl] = bias_s[hh][rl];
    }
}

// ---------------- bias transpose: bias2[h][k][q] = bias3[h][q*256+k] ----------------
__global__ __launch_bounds__(256) void biastr_kernel(const float* __restrict__ bias3,
                                                     float* __restrict__ bias2) {
    __shared__ float T[64][68];
    int t = threadIdx.x;
    int h = blockIdx.x >> 4;
    int q0 = ((blockIdx.x >> 2) & 3) * 64, k0 = (blockIdx.x & 3) * 64;
#pragma unroll
    for (int i = 0; i < 4; i++) {
        int id = i * 256 + t;
        int r = id >> 4, cb = id & 15;
        f32x4 val = *reinterpret_cast<const f32x4*>(&bias3[h * NN + (q0 + r) * 256 + k0 + cb * 4]);
        *reinterpret_cast<f32x4*>(&T[r][cb * 4]) = val;
    }
    __syncthreads();
#pragma unroll
    for (int i = 0; i < 4; i++) {
        int id = i * 256 + t;
        int kr = id >> 4, qb = id & 15;
        f32x4 o;
#pragma unroll
        for (int j = 0; j < 4; j++) o[j] = T[qb * 4 + j][kr];
        *reinterpret_cast<f32x4*>(&bias2[h * NN + (k0 + kr) * 256 + q0 + qb * 4]) = o;
    }
}

// ---------- fused G + QKV projection + flash attention per (b,h) ----------
// z [row][128]; wt[m][out][in]; bias2 [h][key][q]; om2/gm2 head-major [h][row][32]
// launch_bounds (256,3): ~170 unified VGPR+AGPR per wave. (256,4) caps at 128
// and spills ~60-120MB of scratch (R8, R10: both regressed badly). Occupancy
// lever is CLOSED; this round pipelines the QK->softmax->PV chain instead.
__global__ __launch_bounds__(256, 3) void fat_kernel(const bf16_t* __restrict__ z,
                                                     const bf16_t* __restrict__ wt,
                                                     const float* __restrict__ bias2,
                                                     bf16_t* __restrict__ om2,
                                                     bf16_t* __restrict__ gm2) {
    __shared__ bf16_t Kh[256][44];   // [key][c] padded -> conflict-free b128
    __shared__ bf16_t Vt[32][268];   // [c][key] padded -> 2-way b64 (free)
    int t = threadIdx.x;
    int b = blockIdx.x >> 2, h = blockIdx.x & 3;
    int w = t >> 6, lane = t & 63;
    int rsel = lane & 31, hi = lane >> 5;
    int hi8 = hi * 8, hi4 = hi * 4;
    bool lo = (hi == 0);
    const float SCL2 = 0.17677669529663687f * 1.4426950408889634f;  // scale * log2(e)
    const bf16_t* zr0 = z + (size_t)(b * 256 + w * 64 + rsel) * 128;
    const bf16_t* zr1 = zr0 + 32 * 128;

    // ---- G phase: g = sigmoid(z @ Wg[:, h*32..]) for this wave's 64 rows ----
    {
        const bf16_t* wgr = wt + (size_t)(3 * 128 + h * 32 + rsel) * 128;
        f32x16 ag0, ag1;
#pragma unroll
        for (int i = 0; i < 16; i++) { ag0[i] = 0.f; ag1[i] = 0.f; }
#pragma unroll
        for (int ks = 0; ks < 8; ks++) {
            int d = ks * 16 + hi8;
            bf16x8 zb0 = *reinterpret_cast<const bf16x8*>(zr0 + d);
            bf16x8 zb1 = *reinterpret_cast<const bf16x8*>(zr1 + d);
            bf16x8 ag = *reinterpret_cast<const bf16x8*>(wgr + d);
            ag0 = __builtin_amdgcn_mfma_f32_32x32x16_bf16(ag, zb0, ag0, 0, 0, 0);
            ag1 = __builtin_amdgcn_mfma_f32_32x32x16_bf16(ag, zb1, ag1, 0, 0, 0);
        }
#pragma unroll
        for (int i = 0; i < 16; i++) {
            ag0[i] = 1.0f / (1.0f + __expf(-ag0[i]));
            ag1[i] = 1.0f / (1.0f + __expf(-ag1[i]));
        }
        bf16x8 g0, g1;
        bf16_t* grow = gm2 + ((size_t)h * NN + b * 256 + w * 64 + rsel) * 32;
        packX(ag0, lo, g0, g1);
        *reinterpret_cast<bf16x8*>(grow + hi8) = g0;
        *reinterpret_cast<bf16x8*>(grow + 16 + hi8) = g1;
        packX(ag1, lo, g0, g1);
        *reinterpret_cast<bf16x8*>(grow + 32 * 32 + hi8) = g0;
        *reinterpret_cast<bf16x8*>(grow + 32 * 32 + 16 + hi8) = g1;
    }

    // ---- QKV GEMMs (swapped): C[c, row] ----
    const bf16_t* wqr = wt + (size_t)(0 * 128 + h * 32 + rsel) * 128;
    const bf16_t* wkr = wt + (size_t)(1 * 128 + h * 32 + rsel) * 128;
    const bf16_t* wvr = wt + (size_t)(2 * 128 + h * 32 + rsel) * 128;
    f32x16 aq0, aq1, ak0, ak1, av0, av1;
#pragma unroll
    for (int i = 0; i < 16; i++) {
        aq0[i] = 0.f; aq1[i] = 0.f; ak0[i] = 0.f;
        ak1[i] = 0.f; av0[i] = 0.f; av1[i] = 0.f;
    }
#pragma unroll
    for (int ks = 0; ks < 8; ks++) {
        int d = ks * 16 + hi8;
        bf16x8 zb0 = *reinterpret_cast<const bf16x8*>(zr0 + d);
        bf16x8 zb1 = *reinterpret_cast<const bf16x8*>(zr1 + d);
        bf16x8 aq = *reinterpret_cast<const bf16x8*>(wqr + d);
        bf16x8 ak = *reinterpret_cast<const bf16x8*>(wkr + d);
        bf16x8 av = *reinterpret_cast<const bf16x8*>(wvr + d);
        aq0 = __builtin_amdgcn_mfma_f32_32x32x16_bf16(aq, zb0, aq0, 0, 0, 0);
        aq1 = __builtin_amdgcn_mfma_f32_32x32x16_bf16(aq, zb1, aq1, 0, 0, 0);
        ak0 = __builtin_amdgcn_mfma_f32_32x32x16_bf16(ak, zb0, ak0, 0, 0, 0);
        ak1 = __builtin_amdgcn_mfma_f32_32x32x16_bf16(ak, zb1, ak1, 0, 0, 0);
        av0 = __builtin_amdgcn_mfma_f32_32x32x16_bf16(av, zb0, av0, 0, 0, 0);
        av1 = __builtin_amdgcn_mfma_f32_32x32x16_bf16(av, zb1, av1, 0, 0, 0);
    }
    // K -> LDS (packed b128 writes, attn A-frag layout)
    {
        bf16x8 f0, f1;
        int key0 = w * 64 + rsel;
        packX(ak0, lo, f0, f1);
        *reinterpret_cast<bf16x8*>(&Kh[key0][hi8]) = f0;
        *reinterpret_cast<bf16x8*>(&Kh[key0][16 + hi8]) = f1;
        packX(ak1, lo, f0, f1);
        *reinterpret_cast<bf16x8*>(&Kh[key0 + 32][hi8]) = f0;
        *reinterpret_cast<bf16x8*>(&Kh[key0 + 32][16 + hi8]) = f1;
    }
    // V -> LDS transposed (scalar b16 stores, identity key order)
    {
        int key0 = w * 64 + rsel;
#pragma unroll
        for (int r = 0; r < 16; r++) {
            int c = (r & 3) + 8 * (r >> 2) + hi4;
            Vt[c][key0] = (bf16_t)av0[r];
            Vt[c][key0 + 32] = (bf16_t)av1[r];
        }
    }
    // Q -> register B-frags
    bf16x8 qf[2][2];
    packX(aq0, lo, qf[0][0], qf[0][1]);
    packX(aq1, lo, qf[1][0], qf[1][1]);
    __syncthreads();

    // ---- flash attention, QK-ahead software pipeline ----
#pragma unroll
    for (int qt = 0; qt < 2; qt++) {
        int qpos = w * 64 + qt * 32 + rsel;
        bf16x8 qf0 = qf[qt][0];
        bf16x8 qf1 = qf[qt][1];
        const float* bq = bias2 + (size_t)h * NN + qpos;  // + key*256

        f32x16 of;
#pragma unroll
        for (int i = 0; i < 16; i++) of[i] = 0.f;
        float m = -1e30f, l = 0.f;

        // prologue: scores for kt=0 and bias for kt=0
        f32x16 scur;
        {
            bf16x8 k0 = *reinterpret_cast<bf16x8*>(&Kh[rsel][hi8]);
            bf16x8 k1 = *reinterpret_cast<bf16x8*>(&Kh[rsel][16 + hi8]);
#pragma unroll
            for (int i = 0; i < 16; i++) scur[i] = 0.f;
            scur = __builtin_amdgcn_mfma_f32_32x32x16_bf16(k0, qf0, scur, 0, 0, 0);
            scur = __builtin_amdgcn_mfma_f32_32x32x16_bf16(k1, qf1, scur, 0, 0, 0);
        }
        float bv[16];
#pragma unroll
        for (int e = 0; e < 16; e++) {
            int key = 8 * (e >> 2) + hi4 + (e & 3);
            bv[e] = bq[(size_t)key * 256];
        }

#pragma unroll
        for (int kt = 0; kt < 8; kt++) {
            // issue NEXT tile's QK^T + bias loads first: MFMA pipe + L2 loads
            // run underneath this tile's VALU softmax
            f32x16 snx;
            float bvn[16];
            if (kt < 7) {
                bf16x8 k0n = *reinterpret_cast<bf16x8*>(&Kh[(kt + 1) * 32 + rsel][hi8]);
                bf16x8 k1n = *reinterpret_cast<bf16x8*>(&Kh[(kt + 1) * 32 + rsel][16 + hi8]);
#pragma unroll
                for (int i = 0; i < 16; i++) snx[i] = 0.f;
                __builtin_amdgcn_s_setprio(1);
                snx = __builtin_amdgcn_mfma_f32_32x32x16_bf16(k0n, qf0, snx, 0, 0, 0);
                snx = __builtin_amdgcn_mfma_f32_32x32x16_bf16(k1n, qf1, snx, 0, 0, 0);
                __builtin_amdgcn_s_setprio(0);
#pragma unroll
                for (int e = 0; e < 16; e++) {
                    int key = (kt + 1) * 32 + 8 * (e >> 2) + hi4 + (e & 3);
                    bvn[e] = bq[(size_t)key * 256];
                }
            }
            // softmax on current tile
            float tm[8];
#pragma unroll
            for (int e = 0; e < 16; e++) scur[e] = scur[e] * SCL2 + bv[e];
#pragma unroll
            for (int e = 0; e < 8; e++) tm[e] = fmaxf(scur[e], scur[e + 8]);
#pragma unroll
            for (int st = 4; st >= 1; st >>= 1)
#pragma unroll
                for (int e = 0; e < st; e++) tm[e] = fmaxf(tm[e], tm[e + st]);
            float pm = fmaxf(tm[0], __shfl_xor(tm[0], 32));
            // exact defer-max: rescale only if some lane's max grew
            if (__any(pm > m)) {
                float nm = fmaxf(m, pm);
                float al = __builtin_amdgcn_exp2f(m - nm);
                m = nm;
                l *= al;
#pragma unroll
                for (int i = 0; i < 16; i++) of[i] *= al;
            }
            float ts[8];
#pragma unroll
            for (int e = 0; e < 16; e++) scur[e] = __builtin_amdgcn_exp2f(scur[e] - m);
#pragma unroll
            for (int e = 0; e < 8; e++) ts[e] = scur[e] + scur[e + 8];
#pragma unroll
            for (int st = 4; st >= 1; st >>= 1)
#pragma unroll
                for (int e = 0; e < st; e++) ts[e] += ts[e + st];
            l += ts[0];
            // P fragments in native C-layout key order (no cross-lane pack)
            bf16x8 pf0 = frag4(pk2(scur[0], scur[1]), pk2(scur[2], scur[3]),
                               pk2(scur[4], scur[5]), pk2(scur[6], scur[7]));
            bf16x8 pf1 = frag4(pk2(scur[8], scur[9]), pk2(scur[10], scur[11]),
                               pk2(scur[12], scur[13]), pk2(scur[14], scur[15]));
            // V fragments with the SAME key order: paired b64 reads
            bf16x8 va = cat44(*reinterpret_cast<bf16x4*>(&Vt[rsel][kt * 32 + hi4]),
                              *reinterpret_cast<bf16x4*>(&Vt[rsel][kt * 32 + 8 + hi4]));
            bf16x8 vb = cat44(*reinterpret_cast<bf16x4*>(&Vt[rsel][kt * 32 + 16 + hi4]),
                              *reinterpret_cast<bf16x4*>(&Vt[rsel][kt * 32 + 24 + hi4]));
            __builtin_amdgcn_s_setprio(1);
            of = __builtin_amdgcn_mfma_f32_32x32x16_bf16(va, pf0, of, 0, 0, 0);
            of = __builtin_amdgcn_mfma_f32_32x32x16_bf16(vb, pf1, of, 0, 0, 0);
            __builtin_amdgcn_s_setprio(0);
            if (kt < 7) {
                scur = snx;
#pragma unroll
                for (int e = 0; e < 16; e++) bv[e] = bvn[e];
            }
        }

        l += __shfl_xor(l, 32);
        float linv = 1.0f / l;
#pragma unroll
        for (int i = 0; i < 16; i++) of[i] *= linv;
        bf16x8 o0, o1;
        packX(of, lo, o0, o1);
        bf16_t* orow = om2 + ((size_t)h * NN + b * 256 + qpos) * 32;
        *reinterpret_cast<bf16x8*>(orow + hi8) = o0;
        *reinterpret_cast<bf16x8*>(orow + 16 + hi8) = o1;
    }
}

// ---------------- final: out = (o*g) @ Wo, fp32 out, LDS-staged epilogue ----------
__global__ __launch_bounds__(256) void final_kernel(const bf16_t* __restrict__ om2,
                                                    const bf16_t* __restrict__ gm2,
                                                    const bf16_t* __restrict__ wot,
                                                    float* __restrict__ out) {
    __shared__ __align__(16) char smraw[64 * 136 * 2];
    bf16_t(*As)[136] = reinterpret_cast<bf16_t(*)[136]>(smraw);
    float(*Of)[68] = reinterpret_cast<float(*)[68]>(smraw);
    int t = threadIdx.x;
    int rb = blockIdx.x;
#pragma unroll
    for (int i = 0; i < 4; i++) {
        int c = i * 256 + t;
        int r = c >> 4, off = (c & 15) * 8;
        size_t hm = ((size_t)(off >> 5) * NN + rb * 64 + r) * 32 + (off & 31);
        bf16x8 o8 = *reinterpret_cast<const bf16x8*>(&om2[hm]);
        bf16x8 g8 = *reinterpret_cast<const bf16x8*>(&gm2[hm]);
        bf16x8 p8;
#pragma unroll
        for (int e = 0; e < 8; e++) p8[e] = (bf16_t)((float)o8[e] * (float)g8[e]);
        *reinterpret_cast<bf16x8*>(&As[r][off]) = p8;
    }
    __syncthreads();
    int w = t >> 6, lane = t & 63;
    int lx = lane & 15, ly = lane >> 4;
    int m0 = (w >> 1) * 32, n0 = (w & 1) * 32;
    bf16x8 af[2][4];
#pragma unroll
    for (int mt = 0; mt < 2; mt++)
#pragma unroll
        for (int ks = 0; ks < 4; ks++)
            af[mt][ks] = *reinterpret_cast<bf16x8*>(&As[m0 + mt * 16 + lx][ks * 32 + ly * 8]);
    __syncthreads();  // As dead; Of may alias

    for (int half = 0; half < 2; half++) {
        int nc0 = half * 64;
        bf16x8 bfr[2][4];
#pragma unroll
        for (int nt = 0; nt < 2; nt++)
#pragma unroll
            for (int ks = 0; ks < 4; ks++)
                bfr[nt][ks] = *reinterpret_cast<const bf16x8*>(
                    &wot[(nc0 + n0 + nt * 16 + lx) * 128 + ks * 32 + ly * 8]);
        f32x4 acc[2][2];
#pragma unroll
        for (int mt = 0; mt < 2; mt++)
#pragma unroll
            for (int nt = 0; nt < 2; nt++) acc[mt][nt] = (f32x4){0.f, 0.f, 0.f, 0.f};
#pragma unroll
        for (int ks = 0; ks < 4; ks++)
#pragma unroll
            for (int mt = 0; mt < 2; mt++)
#pragma unroll
                for (int nt = 0; nt < 2; nt++)
                    acc[mt][nt] = __builtin_amdgcn_mfma_f32_16x16x32_bf16(af[mt][ks], bfr[nt][ks], acc[mt][nt], 0, 0, 0);
#pragma unroll
        for (int mt = 0; mt < 2; mt++)
#pragma unroll
            for (int nt = 0; nt < 2; nt++)
#pragma unroll
                for (int r = 0; r < 4; r++)
                    Of[m0 + mt * 16 + ly * 4 + r][n0 + nt * 16 + lx] = acc[mt][nt][r];
        __syncthreads();
#pragma unroll
        for (int j = 0; j < 4; j++) {
            int ch = j * 256 + t;
            int r = ch >> 4, cb = ch & 15;
            f32x4 val = *reinterpret_cast<f32x4*>(&Of[r][cb * 4]);
            *reinterpret_cast<f32x4*>(&out[(rb * 64 + r) * 128 + nc0 + cb * 4]) = val;
        }
        __syncthreads();
    }
}

extern "C" void kernel_launch(void* const* d_in, const int* in_sizes, int n_in,
                              void* d_out, int out_size, void* d_ws, size_t ws_size,
                              hipStream_t stream) {
    const float* x   = (const float*)d_in[0];
    const float* lnw = (const float*)d_in[1];
    const float* lnb = (const float*)d_in[2];
    const float* Wb  = (const float*)d_in[3];
    const float* Wq  = (const float*)d_in[4];
    const float* Wk  = (const float*)d_in[5];
    const float* Wv  = (const float*)d_in[6];
    const float* Wg  = (const float*)d_in[7];
    const float* Wo  = (const float*)d_in[8];
    float* out = (float*)d_out;

    char* ws = (char*)d_ws;
    const size_t MAT = (size_t)NN * 128 * sizeof(bf16_t);  // 16 MB
    bf16_t* z     = (bf16_t*)(ws);
    bf16_t* gmat  = (bf16_t*)(ws + MAT);                     // head-major
    bf16_t* omat  = (bf16_t*)(ws + 2 * MAT);                 // head-major
    bf16_t* wt    = (bf16_t*)(ws + 3 * MAT);                 // 5 * 128*128 bf16 = 160KB
    float*  bias3 = (float*)(ws + 3 * MAT + (1 << 20));      // 1MB
    float*  bias2 = (float*)(ws + 3 * MAT + (2 << 20));      // 1MB

    convw_kernel<<<640, 128, 0, stream>>>(Wq, Wk, Wv, Wg, Wo, wt);
    ln_kernel<<<8192, 256, 0, stream>>>(x, lnw, lnb, Wb, z, bias3);
    biastr_kernel<<<64, 256, 0, stream>>>(bias3, bias2);
    fat_kernel<<<1024, 256, 0, stream>>>(z, wt, bias2, omat, gmat);
    final_kernel<<<1024, 256, 0, stream>>>(omat, gmat, wt + 4 * 16384, out);
}

// Round 12
// 86.684 us; speedup vs baseline: 1.4135x; 1.1308x over previous
//
#include <hip/hip_runtime.h>
#include <hip/hip_bf16.h>

#define NN 65536   // N*N rows
#define DD 128
#define NH 4
#define HDIM 32

typedef __bf16 bf16_t;
typedef __bf16 bf16x8 __attribute__((ext_vector_type(8)));
typedef __bf16 bf16x4 __attribute__((ext_vector_type(4)));
typedef __bf16 bf16x2 __attribute__((ext_vector_type(2)));
typedef float f32x4 __attribute__((ext_vector_type(4)));
typedef float f32x16 __attribute__((ext_vector_type(16)));
typedef unsigned int u32;
typedef unsigned int u32x4 __attribute__((ext_vector_type(4)));

__device__ inline u32 pk2(float a, float b) {
    bf16x2 t;
    t[0] = (bf16_t)a;
    t[1] = (bf16_t)b;
    return __builtin_bit_cast(u32, t);
}
__device__ inline bf16x8 frag4(u32 a, u32 b, u32 c, u32 d) {
    u32x4 t = {a, b, c, d};
    return __builtin_bit_cast(bf16x8, t);
}
__device__ inline bf16x8 cat44(bf16x4 a, bf16x4 b) {
    bf16x8 r;
#pragma unroll
    for (int j = 0; j < 4; j++) { r[j] = a[j]; r[4 + j] = b[j]; }
    return r;
}
// VERIFIED (R2-R6): pack C-layout (col=lane&31, c=(r&3)+8*(r>>2)+4*hi) into two
// contiguous frags via shfl. f0 = lane's c[hi*8..+8), f1 = c[16+hi*8..+8).
__device__ inline void packX(const f32x16& s, bool lo, bf16x8& f0, bf16x8& f1) {
    u32 wv[8];
#pragma unroll
    for (int g = 0; g < 4; g++) {
        wv[2 * g] = pk2(s[4 * g], s[4 * g + 1]);
        wv[2 * g + 1] = pk2(s[4 * g + 2], s[4 * g + 3]);
    }
    u32 p0 = __shfl_xor(wv[0], 32), p1 = __shfl_xor(wv[1], 32);
    u32 p2 = __shfl_xor(wv[2], 32), p3 = __shfl_xor(wv[3], 32);
    u32 p4 = __shfl_xor(wv[4], 32), p5 = __shfl_xor(wv[5], 32);
    u32 p6 = __shfl_xor(wv[6], 32), p7 = __shfl_xor(wv[7], 32);
    f0 = frag4(lo ? wv[0] : p2, lo ? wv[1] : p3, lo ? p0 : wv[2], lo ? p1 : wv[3]);
    f1 = frag4(lo ? wv[4] : p6, lo ? wv[5] : p7, lo ? p4 : wv[6], lo ? p5 : wv[7]);
}

// ------------- weight conversion to fragment-ready layouts (coalesced reads in hot kernels)
// blocks 0..15: wf[(m*4+h)][ks][rsel][16] = W_m[ks*16+e][h*32+rsel]  (m: q,k,v,g)
// blocks 16..23: wfO[oc][ks][lx][ly*8+e] = Wo[ks*32+ly*8+e][oc*16+lx]
__global__ __launch_bounds__(256) void convw_kernel(const float* __restrict__ Wq,
                                                    const float* __restrict__ Wk,
                                                    const float* __restrict__ Wv,
                                                    const float* __restrict__ Wg,
                                                    const float* __restrict__ Wo,
                                                    bf16_t* __restrict__ wf,
                                                    bf16_t* __restrict__ wfO) {
    __shared__ float Ws[128][33];
    __shared__ float Ws2[128][17];
    int blk = blockIdx.x, t = threadIdx.x;
    if (blk < 16) {
        int m = blk >> 2, h = blk & 3;
        const float* W = (m == 0) ? Wq : (m == 1) ? Wk : (m == 2) ? Wv : Wg;
#pragma unroll
        for (int p = 0; p < 16; p++) {
            int d = p * 8 + (t >> 5), o = t & 31;
            Ws[d][o] = W[d * 128 + h * 32 + o];
        }
        __syncthreads();
        bf16_t* dst = wf + (size_t)blk * 4096;
#pragma unroll
        for (int p = 0; p < 16; p++) {
            int j = p * 256 + t;
            int ks = j >> 9, rsel = (j >> 4) & 31, e = j & 15;
            dst[j] = (bf16_t)Ws[ks * 16 + e][rsel];
        }
    } else {
        int oc = blk - 16;  // 0..7
#pragma unroll
        for (int p = 0; p < 8; p++) {
            int d = p * 16 + (t >> 4), o = t & 15;
            Ws2[d][o] = Wo[d * 128 + oc * 16 + o];
        }
        __syncthreads();
        bf16_t* dst = wfO + (size_t)oc * 2048;
#pragma unroll
        for (int p = 0; p < 8; p++) {
            int j = p * 256 + t;
            int ks = j >> 9, rem = j & 511;
            int lx = rem >> 5, ly = (rem >> 3) & 3, e = j & 7;
            dst[j] = (bf16_t)Ws2[ks * 32 + ly * 8 + e][lx];
        }
    }
}

// ---------------- LayerNorm + bias; z emitted in fragment-ready zF layout ----------------
// zF[rowgroup=row>>5][ks][rsel=row&31][16]; bias3[h][row] (exp2 domain)
__global__ __launch_bounds__(256) void ln_kernel(const float* __restrict__ x,
                                                 const float* __restrict__ lw,
                                                 const float* __restrict__ lb,
                                                 const float* __restrict__ Wb,
                                                 bf16_t* __restrict__ zF,
                                                 float* __restrict__ bias3) {
    __shared__ bf16_t zs[4096];        // [ks][rsel][16], 8KB
    __shared__ float bias_s[4][32];
    int t = threadIdx.x;
    int g = t >> 5, l32 = t & 31;
    int rowbase = blockIdx.x * 32;
    int d0 = l32 * 4;
    f32x4 lwv = *reinterpret_cast<const f32x4*>(&lw[d0]);
    f32x4 lbv = *reinterpret_cast<const f32x4*>(&lb[d0]);
    f32x4 wbj[4];
#pragma unroll
    for (int j = 0; j < 4; j++) wbj[j] = *reinterpret_cast<const f32x4*>(&Wb[(d0 + j) * 4]);
#pragma unroll
    for (int r4 = 0; r4 < 4; r4++) {
        int roff = r4 * 8 + g;
        int row = rowbase + roff;
        f32x4 v = *reinterpret_cast<const f32x4*>(&x[(size_t)row * 128 + d0]);
        float s1 = v[0] + v[1] + v[2] + v[3];
        float s2 = v[0] * v[0] + v[1] * v[1] + v[2] * v[2] + v[3] * v[3];
#pragma unroll
        for (int m = 1; m < 32; m <<= 1) {
            s1 += __shfl_xor(s1, m);
            s2 += __shfl_xor(s2, m);
        }
        float mu = s1 * (1.0f / 128.0f);
        float var = s2 * (1.0f / 128.0f) - mu * mu;
        float rs = rsqrtf(var + 1e-5f);
        float zv[4];
        bf16x4 pk;
#pragma unroll
        for (int j = 0; j < 4; j++) {
            zv[j] = (v[j] - mu) * rs * lwv[j] + lbv[j];
            pk[j] = (bf16_t)zv[j];
        }
        *reinterpret_cast<bf16x4*>(&zs[(l32 >> 2) * 512 + roff * 16 + (l32 & 3) * 4]) = pk;
        f32x4 pb = {0.f, 0.f, 0.f, 0.f};
#pragma unroll
        for (int j = 0; j < 4; j++)
#pragma unroll
            for (int hh = 0; hh < 4; hh++) pb[hh] += zv[j] * wbj[j][hh];
#pragma unroll
        for (int m = 1; m < 32; m <<= 1) {
#pragma unroll
            for (int hh = 0; hh < 4; hh++) pb[hh] += __shfl_xor(pb[hh], m);
        }
        if (l32 == 0) {
#pragma unroll
            for (int hh = 0; hh < 4; hh++)
                bias_s[hh][roff] = pb[hh] * 1.4426950408889634f;
        }
    }
    __syncthreads();
    if (t < 128) {
        bias3[(size_t)(t >> 5) * NN + rowbase + (t & 31)] = bias_s[t >> 5][t & 31];
    }
    bf16_t* dst = zF + (size_t)blockIdx.x * 4096;
#pragma unroll
    for (int p = 0; p < 2; p++) {
        int c = p * 2048 + t * 8;
        *reinterpret_cast<bf16x8*>(dst + c) = *reinterpret_cast<bf16x8*>(zs + c);
    }
}

// ---------------- bias transpose: bias2[h][k][q] = bias3[h][q*256+k] ----------------
__global__ __launch_bounds__(256) void biastr_kernel(const float* __restrict__ bias3,
                                                     float* __restrict__ bias2) {
    __shared__ float T[64][68];
    int t = threadIdx.x;
    int h = blockIdx.x >> 4;
    int q0 = ((blockIdx.x >> 2) & 3) * 64, k0 = (blockIdx.x & 3) * 64;
#pragma unroll
    for (int i = 0; i < 4; i++) {
        int id = i * 256 + t;
        int r = id >> 4, cb = id & 15;
        f32x4 val = *reinterpret_cast<const f32x4*>(&bias3[h * NN + (q0 + r) * 256 + k0 + cb * 4]);
        *reinterpret_cast<f32x4*>(&T[r][cb * 4]) = val;
    }
    __syncthreads();
#pragma unroll
    for (int i = 0; i < 4; i++) {
        int id = i * 256 + t;
        int kr = id >> 4, qb = id & 15;
        f32x4 o;
#pragma unroll
        for (int j = 0; j < 4; j++) o[j] = T[qb * 4 + j][kr];
        *reinterpret_cast<f32x4*>(&bias2[h * NN + (k0 + kr) * 256 + q0 + qb * 4]) = o;
    }
}

// ---------- fused G + QKV projection + flash attention per (b,h) ----------
// zF fragment-ready; wf fragment-ready; bias2 [h][key][q]; om2/gm2 head-major [h][row][32]
// launch_bounds (256,3): ~170 unified VGPR+AGPR/wave; (256,4) spills (R8/R10).
__global__ __launch_bounds__(256, 3) void fat_kernel(const bf16_t* __restrict__ zF,
                                                     const bf16_t* __restrict__ wf,
                                                     const float* __restrict__ bias2,
                                                     bf16_t* __restrict__ om2,
                                                     bf16_t* __restrict__ gm2) {
    __shared__ bf16_t Kh[256][44];   // [key][c] padded -> conflict-free b128
    __shared__ bf16_t Vt[32][268];   // [c][key] padded -> 2-way b64 (free)
    int t = threadIdx.x;
    int b = blockIdx.x >> 2, h = blockIdx.x & 3;
    int w = t >> 6, lane = t & 63;
    int rsel = lane & 31, hi = lane >> 5;
    int hi8 = hi * 8, hi4 = hi * 4;
    bool lo = (hi == 0);
    const float SCL2 = 0.17677669529663687f * 1.4426950408889634f;  // scale * log2(e)
    // fragment-ready z: 32-row groups; wave w uses groups b*8+w*2 and +1
    const bf16_t* zg0 = zF + (size_t)(b * 8 + w * 2) * 4096;
    const bf16_t* zg1 = zg0 + 4096;
    int fro = rsel * 16 + hi8;   // per-lane offset within [ks] slab

    // ---- G phase: g = sigmoid(z @ Wg[:, h*32..]) for this wave's 64 rows ----
    {
        const bf16_t* wg = wf + (size_t)(3 * 4 + h) * 4096;
        f32x16 ag0, ag1;
#pragma unroll
        for (int i = 0; i < 16; i++) { ag0[i] = 0.f; ag1[i] = 0.f; }
#pragma unroll
        for (int ks = 0; ks < 8; ks++) {
            int off = ks * 512 + fro;
            bf16x8 zb0 = *reinterpret_cast<const bf16x8*>(zg0 + off);
            bf16x8 zb1 = *reinterpret_cast<const bf16x8*>(zg1 + off);
            bf16x8 ag = *reinterpret_cast<const bf16x8*>(wg + off);
            ag0 = __builtin_amdgcn_mfma_f32_32x32x16_bf16(ag, zb0, ag0, 0, 0, 0);
            ag1 = __builtin_amdgcn_mfma_f32_32x32x16_bf16(ag, zb1, ag1, 0, 0, 0);
        }
#pragma unroll
        for (int i = 0; i < 16; i++) {
            ag0[i] = 1.0f / (1.0f + __expf(-ag0[i]));
            ag1[i] = 1.0f / (1.0f + __expf(-ag1[i]));
        }
        bf16x8 g0, g1;
        bf16_t* grow = gm2 + ((size_t)h * NN + b * 256 + w * 64 + rsel) * 32;
        packX(ag0, lo, g0, g1);
        *reinterpret_cast<bf16x8*>(grow + hi8) = g0;
        *reinterpret_cast<bf16x8*>(grow + 16 + hi8) = g1;
        packX(ag1, lo, g0, g1);
        *reinterpret_cast<bf16x8*>(grow + 32 * 32 + hi8) = g0;
        *reinterpret_cast<bf16x8*>(grow + 32 * 32 + 16 + hi8) = g1;
    }

    // ---- QKV GEMMs (swapped): C[c, row] ----
    const bf16_t* wq = wf + (size_t)(0 * 4 + h) * 4096;
    const bf16_t* wk = wf + (size_t)(1 * 4 + h) * 4096;
    const bf16_t* wv = wf + (size_t)(2 * 4 + h) * 4096;
    f32x16 aq0, aq1, ak0, ak1, av0, av1;
#pragma unroll
    for (int i = 0; i < 16; i++) {
        aq0[i] = 0.f; aq1[i] = 0.f; ak0[i] = 0.f;
        ak1[i] = 0.f; av0[i] = 0.f; av1[i] = 0.f;
    }
#pragma unroll
    for (int ks = 0; ks < 8; ks++) {
        int off = ks * 512 + fro;
        bf16x8 zb0 = *reinterpret_cast<const bf16x8*>(zg0 + off);
        bf16x8 zb1 = *reinterpret_cast<const bf16x8*>(zg1 + off);
        bf16x8 aq = *reinterpret_cast<const bf16x8*>(wq + off);
        bf16x8 ak = *reinterpret_cast<const bf16x8*>(wk + off);
        bf16x8 av = *reinterpret_cast<const bf16x8*>(wv + off);
        aq0 = __builtin_amdgcn_mfma_f32_32x32x16_bf16(aq, zb0, aq0, 0, 0, 0);
        aq1 = __builtin_amdgcn_mfma_f32_32x32x16_bf16(aq, zb1, aq1, 0, 0, 0);
        ak0 = __builtin_amdgcn_mfma_f32_32x32x16_bf16(ak, zb0, ak0, 0, 0, 0);
        ak1 = __builtin_amdgcn_mfma_f32_32x32x16_bf16(ak, zb1, ak1, 0, 0, 0);
        av0 = __builtin_amdgcn_mfma_f32_32x32x16_bf16(av, zb0, av0, 0, 0, 0);
        av1 = __builtin_amdgcn_mfma_f32_32x32x16_bf16(av, zb1, av1, 0, 0, 0);
    }
    // K -> LDS (packed b128 writes, attn A-frag layout)
    {
        bf16x8 f0, f1;
        int key0 = w * 64 + rsel;
        packX(ak0, lo, f0, f1);
        *reinterpret_cast<bf16x8*>(&Kh[key0][hi8]) = f0;
        *reinterpret_cast<bf16x8*>(&Kh[key0][16 + hi8]) = f1;
        packX(ak1, lo, f0, f1);
        *reinterpret_cast<bf16x8*>(&Kh[key0 + 32][hi8]) = f0;
        *reinterpret_cast<bf16x8*>(&Kh[key0 + 32][16 + hi8]) = f1;
    }
    // V -> LDS transposed (scalar b16 stores, identity key order)
    {
        int key0 = w * 64 + rsel;
#pragma unroll
        for (int r = 0; r < 16; r++) {
            int c = (r & 3) + 8 * (r >> 2) + hi4;
            Vt[c][key0] = (bf16_t)av0[r];
            Vt[c][key0 + 32] = (bf16_t)av1[r];
        }
    }
    // Q -> register B-frags
    bf16x8 qf[2][2];
    packX(aq0, lo, qf[0][0], qf[0][1]);
    packX(aq1, lo, qf[1][0], qf[1][1]);
    __syncthreads();

    // ---- flash attention ----
#pragma unroll
    for (int qt = 0; qt < 2; qt++) {
        int qpos = w * 64 + qt * 32 + rsel;
        bf16x8 qf0 = qf[qt][0];
        bf16x8 qf1 = qf[qt][1];
        const float* bq = bias2 + (size_t)h * NN + qpos;  // + key*256

        f32x16 of;
#pragma unroll
        for (int i = 0; i < 16; i++) of[i] = 0.f;
        float m = -1e30f, l = 0.f;

        float bv[16];
#pragma unroll
        for (int e = 0; e < 16; e++) {
            int key = 8 * (e >> 2) + hi4 + (e & 3);
            bv[e] = bq[(size_t)key * 256];
        }
#pragma unroll
        for (int kt = 0; kt < 8; kt++) {
            bf16x8 k0 = *reinterpret_cast<bf16x8*>(&Kh[kt * 32 + rsel][hi8]);
            bf16x8 k1 = *reinterpret_cast<bf16x8*>(&Kh[kt * 32 + rsel][16 + hi8]);
            f32x16 s;
#pragma unroll
            for (int i = 0; i < 16; i++) s[i] = 0.f;
            __builtin_amdgcn_s_setprio(1);
            s = __builtin_amdgcn_mfma_f32_32x32x16_bf16(k0, qf0, s, 0, 0, 0);
            s = __builtin_amdgcn_mfma_f32_32x32x16_bf16(k1, qf1, s, 0, 0, 0);
            __builtin_amdgcn_s_setprio(0);
            // prefetch next chunk's bias
            float bvn[16];
            if (kt < 7) {
#pragma unroll
                for (int e = 0; e < 16; e++) {
                    int key = (kt + 1) * 32 + 8 * (e >> 2) + hi4 + (e & 3);
                    bvn[e] = bq[(size_t)key * 256];
                }
            }
            float tm[8];
#pragma unroll
            for (int e = 0; e < 16; e++) s[e] = s[e] * SCL2 + bv[e];
#pragma unroll
            for (int e = 0; e < 8; e++) tm[e] = fmaxf(s[e], s[e + 8]);
#pragma unroll
            for (int st = 4; st >= 1; st >>= 1)
#pragma unroll
                for (int e = 0; e < st; e++) tm[e] = fmaxf(tm[e], tm[e + st]);
            float pm = fmaxf(tm[0], __shfl_xor(tm[0], 32));
            // exact defer-max: rescale only if some lane's max grew
            if (__any(pm > m)) {
                float nm = fmaxf(m, pm);
                float al = __builtin_amdgcn_exp2f(m - nm);
                m = nm;
                l *= al;
#pragma unroll
                for (int i = 0; i < 16; i++) of[i] *= al;
            }
            float ts[8];
#pragma unroll
            for (int e = 0; e < 16; e++) s[e] = __builtin_amdgcn_exp2f(s[e] - m);
#pragma unroll
            for (int e = 0; e < 8; e++) ts[e] = s[e] + s[e + 8];
#pragma unroll
            for (int st = 4; st >= 1; st >>= 1)
#pragma unroll
                for (int e = 0; e < st; e++) ts[e] += ts[e + st];
            l += ts[0];
            // P fragments in native C-layout key order (no cross-lane pack)
            bf16x8 pf0 = frag4(pk2(s[0], s[1]), pk2(s[2], s[3]),
                               pk2(s[4], s[5]), pk2(s[6], s[7]));
            bf16x8 pf1 = frag4(pk2(s[8], s[9]), pk2(s[10], s[11]),
                               pk2(s[12], s[13]), pk2(s[14], s[15]));
            // V fragments with the SAME key order: paired b64 reads
            bf16x8 va = cat44(*reinterpret_cast<bf16x4*>(&Vt[rsel][kt * 32 + hi4]),
                              *reinterpret_cast<bf16x4*>(&Vt[rsel][kt * 32 + 8 + hi4]));
            bf16x8 vb = cat44(*reinterpret_cast<bf16x4*>(&Vt[rsel][kt * 32 + 16 + hi4]),
                              *reinterpret_cast<bf16x4*>(&Vt[rsel][kt * 32 + 24 + hi4]));
            __builtin_amdgcn_s_setprio(1);
            of = __builtin_amdgcn_mfma_f32_32x32x16_bf16(va, pf0, of, 0, 0, 0);
            of = __builtin_amdgcn_mfma_f32_32x32x16_bf16(vb, pf1, of, 0, 0, 0);
            __builtin_amdgcn_s_setprio(0);
            if (kt < 7) {
#pragma unroll
                for (int e = 0; e < 16; e++) bv[e] = bvn[e];
            }
        }

        l += __shfl_xor(l, 32);
        float linv = 1.0f / l;
#pragma unroll
        for (int i = 0; i < 16; i++) of[i] *= linv;
        bf16x8 o0, o1;
        packX(of, lo, o0, o1);
        bf16_t* orow = om2 + ((size_t)h * NN + b * 256 + qpos) * 32;
        *reinterpret_cast<bf16x8*>(orow + hi8) = o0;
        *reinterpret_cast<bf16x8*>(orow + 16 + hi8) = o1;
    }
}

// ---------------- final: out = (o*g) @ Wo, fp32 out, LDS-staged epilogue ----------
__global__ __launch_bounds__(256) void final_kernel(const bf16_t* __restrict__ om2,
                                                    const bf16_t* __restrict__ gm2,
                                                    const bf16_t* __restrict__ wfO,
                                                    float* __restrict__ out) {
    __shared__ __align__(16) char smraw[64 * 136 * 2];
    bf16_t(*As)[136] = reinterpret_cast<bf16_t(*)[136]>(smraw);
    float(*Of)[68] = reinterpret_cast<float(*)[68]>(smraw);
    int t = threadIdx.x;
    int rb = blockIdx.x;
#pragma unroll
    for (int i = 0; i < 4; i++) {
        int c = i * 256 + t;
        int r = c >> 4, off = (c & 15) * 8;
        size_t hm = ((size_t)(off >> 5) * NN + rb * 64 + r) * 32 + (off & 31);
        bf16x8 o8 = *reinterpret_cast<const bf16x8*>(&om2[hm]);
        bf16x8 g8 = *reinterpret_cast<const bf16x8*>(&gm2[hm]);
        bf16x8 p8;
#pragma unroll
        for (int e = 0; e < 8; e++) p8[e] = (bf16_t)((float)o8[e] * (float)g8[e]);
        *reinterpret_cast<bf16x8*>(&As[r][off]) = p8;
    }
    __syncthreads();
    int w = t >> 6, lane = t & 63;
    int lx = lane & 15, ly = lane >> 4;
    int m0 = (w >> 1) * 32, n0 = (w & 1) * 32;
    bf16x8 af[2][4];
#pragma unroll
    for (int mt = 0; mt < 2; mt++)
#pragma unroll
        for (int ks = 0; ks < 4; ks++)
            af[mt][ks] = *reinterpret_cast<bf16x8*>(&As[m0 + mt * 16 + lx][ks * 32 + ly * 8]);
    __syncthreads();  // As dead; Of may alias

    for (int half = 0; half < 2; half++) {
        int nc0 = half * 64;
        bf16x8 bfr[2][4];
#pragma unroll
        for (int nt = 0; nt < 2; nt++) {
            int oc = ((nc0 + n0) >> 4) + nt;
#pragma unroll
            for (int ks = 0; ks < 4; ks++)
                bfr[nt][ks] = *reinterpret_cast<const bf16x8*>(
                    &wfO[oc * 2048 + ks * 512 + lx * 32 + ly * 8]);
        }
        f32x4 acc[2][2];
#pragma unroll
        for (int mt = 0; mt < 2; mt++)
#pragma unroll
            for (int nt = 0; nt < 2; nt++) acc[mt][nt] = (f32x4){0.f, 0.f, 0.f, 0.f};
#pragma unroll
        for (int ks = 0; ks < 4; ks++)
#pragma unroll
            for (int mt = 0; mt < 2; mt++)
#pragma unroll
                for (int nt = 0; nt < 2; nt++)
                    acc[mt][nt] = __builtin_amdgcn_mfma_f32_16x16x32_bf16(af[mt][ks], bfr[nt][ks], acc[mt][nt], 0, 0, 0);
#pragma unroll
        for (int mt = 0; mt < 2; mt++)
#pragma unroll
            for (int nt = 0; nt < 2; nt++)
#pragma unroll
                for (int r = 0; r < 4; r++)
                    Of[m0 + mt * 16 + ly * 4 + r][n0 + nt * 16 + lx] = acc[mt][nt][r];
        __syncthreads();
#pragma unroll
        for (int j = 0; j < 4; j++) {
            int ch = j * 256 + t;
            int r = ch >> 4, cb = ch & 15;
            f32x4 val = *reinterpret_cast<f32x4*>(&Of[r][cb * 4]);
            *reinterpret_cast<f32x4*>(&out[(rb * 64 + r) * 128 + nc0 + cb * 4]) = val;
        }
        __syncthreads();
    }
}

extern "C" void kernel_launch(void* const* d_in, const int* in_sizes, int n_in,
                              void* d_out, int out_size, void* d_ws, size_t ws_size,
                              hipStream_t stream) {
    const float* x   = (const float*)d_in[0];
    const float* lnw = (const float*)d_in[1];
    const float* lnb = (const float*)d_in[2];
    const float* Wb  = (const float*)d_in[3];
    const float* Wq  = (const float*)d_in[4];
    const float* Wk  = (const float*)d_in[5];
    const float* Wv  = (const float*)d_in[6];
    const float* Wg  = (const float*)d_in[7];
    const float* Wo  = (const float*)d_in[8];
    float* out = (float*)d_out;

    char* ws = (char*)d_ws;
    const size_t MAT = (size_t)NN * 128 * sizeof(bf16_t);  // 16 MB
    bf16_t* zF    = (bf16_t*)(ws);                           // fragment-ready z
    bf16_t* gmat  = (bf16_t*)(ws + MAT);                     // head-major
    bf16_t* omat  = (bf16_t*)(ws + 2 * MAT);                 // head-major
    bf16_t* wf    = (bf16_t*)(ws + 3 * MAT);                 // 16*4096 bf16 = 128KB
    bf16_t* wfO   = (bf16_t*)(ws + 3 * MAT + (128 << 10));   // 8*2048 bf16 = 32KB
    float*  bias3 = (float*)(ws + 3 * MAT + (1 << 20));      // 1MB
    float*  bias2 = (float*)(ws + 3 * MAT + (2 << 20));      // 1MB

    convw_kernel<<<24, 256, 0, stream>>>(Wq, Wk, Wv, Wg, Wo, wf, wfO);
    ln_kernel<<<2048, 256, 0, stream>>>(x, lnw, lnb, Wb, zF, bias3);
    biastr_kernel<<<64, 256, 0, stream>>>(bias3, bias2);
    fat_kernel<<<1024, 256, 0, stream>>>(zF, wf, bias2, omat, gmat);
    final_kernel<<<1024, 256, 0, stream>>>(omat, gmat, wfO, out);
}

// Round 13
// 77.928 us; speedup vs baseline: 1.5724x; 1.1124x over previous
//
#include <hip/hip_runtime.h>
#include <hip/hip_bf16.h>

#define NN 65536   // N*N rows
#define DD 128
#define NH 4
#define HDIM 32

typedef __bf16 bf16_t;
typedef __bf16 bf16x8 __attribute__((ext_vector_type(8)));
typedef __bf16 bf16x4 __attribute__((ext_vector_type(4)));
typedef __bf16 bf16x2 __attribute__((ext_vector_type(2)));
typedef float f32x4 __attribute__((ext_vector_type(4)));
typedef float f32x16 __attribute__((ext_vector_type(16)));
typedef unsigned int u32;
typedef unsigned int u32x4 __attribute__((ext_vector_type(4)));

__device__ inline u32 pk2(float a, float b) {
    bf16x2 t;
    t[0] = (bf16_t)a;
    t[1] = (bf16_t)b;
    return __builtin_bit_cast(u32, t);
}
__device__ inline bf16x8 frag4(u32 a, u32 b, u32 c, u32 d) {
    u32x4 t = {a, b, c, d};
    return __builtin_bit_cast(bf16x8, t);
}
__device__ inline bf16x8 cat44(bf16x4 a, bf16x4 b) {
    bf16x8 r;
#pragma unroll
    for (int j = 0; j < 4; j++) { r[j] = a[j]; r[4 + j] = b[j]; }
    return r;
}
// VERIFIED (R2-R6): pack C-layout (col=lane&31, c=(r&3)+8*(r>>2)+4*hi) into two
// contiguous frags via shfl. f0 = lane's c[hi*8..+8), f1 = c[16+hi*8..+8).
__device__ inline void packX(const f32x16& s, bool lo, bf16x8& f0, bf16x8& f1) {
    u32 wv[8];
#pragma unroll
    for (int g = 0; g < 4; g++) {
        wv[2 * g] = pk2(s[4 * g], s[4 * g + 1]);
        wv[2 * g + 1] = pk2(s[4 * g + 2], s[4 * g + 3]);
    }
    u32 p0 = __shfl_xor(wv[0], 32), p1 = __shfl_xor(wv[1], 32);
    u32 p2 = __shfl_xor(wv[2], 32), p3 = __shfl_xor(wv[3], 32);
    u32 p4 = __shfl_xor(wv[4], 32), p5 = __shfl_xor(wv[5], 32);
    u32 p6 = __shfl_xor(wv[6], 32), p7 = __shfl_xor(wv[7], 32);
    f0 = frag4(lo ? wv[0] : p2, lo ? wv[1] : p3, lo ? p0 : wv[2], lo ? p1 : wv[3]);
    f1 = frag4(lo ? wv[4] : p6, lo ? wv[5] : p7, lo ? p4 : wv[6], lo ? p5 : wv[7]);
}

// ------------- weight conversion to fragment-ready layouts (coalesced reads in hot kernels)
__global__ __launch_bounds__(256) void convw_kernel(const float* __restrict__ Wq,
                                                    const float* __restrict__ Wk,
                                                    const float* __restrict__ Wv,
                                                    const float* __restrict__ Wg,
                                                    const float* __restrict__ Wo,
                                                    bf16_t* __restrict__ wf,
                                                    bf16_t* __restrict__ wfO) {
    __shared__ float Ws[128][33];
    __shared__ float Ws2[128][17];
    int blk = blockIdx.x, t = threadIdx.x;
    if (blk < 16) {
        int m = blk >> 2, h = blk & 3;
        const float* W = (m == 0) ? Wq : (m == 1) ? Wk : (m == 2) ? Wv : Wg;
#pragma unroll
        for (int p = 0; p < 16; p++) {
            int d = p * 8 + (t >> 5), o = t & 31;
            Ws[d][o] = W[d * 128 + h * 32 + o];
        }
        __syncthreads();
        bf16_t* dst = wf + (size_t)blk * 4096;
#pragma unroll
        for (int p = 0; p < 16; p++) {
            int j = p * 256 + t;
            int ks = j >> 9, rsel = (j >> 4) & 31, e = j & 15;
            dst[j] = (bf16_t)Ws[ks * 16 + e][rsel];
        }
    } else {
        int oc = blk - 16;  // 0..7
#pragma unroll
        for (int p = 0; p < 8; p++) {
            int d = p * 16 + (t >> 4), o = t & 15;
            Ws2[d][o] = Wo[d * 128 + oc * 16 + o];
        }
        __syncthreads();
        bf16_t* dst = wfO + (size_t)oc * 2048;
#pragma unroll
        for (int p = 0; p < 8; p++) {
            int j = p * 256 + t;
            int ks = j >> 9, rem = j & 511;
            int lx = rem >> 5, ly = (rem >> 3) & 3, e = j & 7;
            dst[j] = (bf16_t)Ws2[ks * 32 + ly * 8 + e][lx];
        }
    }
}

// ---------------- LayerNorm + bias; z emitted in fragment-ready zF layout ----------------
__global__ __launch_bounds__(256) void ln_kernel(const float* __restrict__ x,
                                                 const float* __restrict__ lw,
                                                 const float* __restrict__ lb,
                                                 const float* __restrict__ Wb,
                                                 bf16_t* __restrict__ zF,
                                                 float* __restrict__ bias3) {
    __shared__ bf16_t zs[4096];        // [ks][rsel][16], 8KB
    __shared__ float bias_s[4][32];
    int t = threadIdx.x;
    int g = t >> 5, l32 = t & 31;
    int rowbase = blockIdx.x * 32;
    int d0 = l32 * 4;
    f32x4 lwv = *reinterpret_cast<const f32x4*>(&lw[d0]);
    f32x4 lbv = *reinterpret_cast<const f32x4*>(&lb[d0]);
    f32x4 wbj[4];
#pragma unroll
    for (int j = 0; j < 4; j++) wbj[j] = *reinterpret_cast<const f32x4*>(&Wb[(d0 + j) * 4]);
#pragma unroll
    for (int r4 = 0; r4 < 4; r4++) {
        int roff = r4 * 8 + g;
        int row = rowbase + roff;
        f32x4 v = *reinterpret_cast<const f32x4*>(&x[(size_t)row * 128 + d0]);
        float s1 = v[0] + v[1] + v[2] + v[3];
        float s2 = v[0] * v[0] + v[1] * v[1] + v[2] * v[2] + v[3] * v[3];
#pragma unroll
        for (int m = 1; m < 32; m <<= 1) {
            s1 += __shfl_xor(s1, m);
            s2 += __shfl_xor(s2, m);
        }
        float mu = s1 * (1.0f / 128.0f);
        float var = s2 * (1.0f / 128.0f) - mu * mu;
        float rs = rsqrtf(var + 1e-5f);
        float zv[4];
        bf16x4 pk;
#pragma unroll
        for (int j = 0; j < 4; j++) {
            zv[j] = (v[j] - mu) * rs * lwv[j] + lbv[j];
            pk[j] = (bf16_t)zv[j];
        }
        *reinterpret_cast<bf16x4*>(&zs[(l32 >> 2) * 512 + roff * 16 + (l32 & 3) * 4]) = pk;
        f32x4 pb = {0.f, 0.f, 0.f, 0.f};
#pragma unroll
        for (int j = 0; j < 4; j++)
#pragma unroll
            for (int hh = 0; hh < 4; hh++) pb[hh] += zv[j] * wbj[j][hh];
#pragma unroll
        for (int m = 1; m < 32; m <<= 1) {
#pragma unroll
            for (int hh = 0; hh < 4; hh++) pb[hh] += __shfl_xor(pb[hh], m);
        }
        if (l32 == 0) {
#pragma unroll
            for (int hh = 0; hh < 4; hh++)
                bias_s[hh][roff] = pb[hh] * 1.4426950408889634f;
        }
    }
    __syncthreads();
    if (t < 128) {
        bias3[(size_t)(t >> 5) * NN + rowbase + (t & 31)] = bias_s[t >> 5][t & 31];
    }
    bf16_t* dst = zF + (size_t)blockIdx.x * 4096;
#pragma unroll
    for (int p = 0; p < 2; p++) {
        int c = p * 2048 + t * 8;
        *reinterpret_cast<bf16x8*>(dst + c) = *reinterpret_cast<bf16x8*>(zs + c);
    }
}

// ---------------- bias transpose: bias2[h][k][q] = bias3[h][q*256+k] ----------------
__global__ __launch_bounds__(256) void biastr_kernel(const float* __restrict__ bias3,
                                                     float* __restrict__ bias2) {
    __shared__ float T[64][68];
    int t = threadIdx.x;
    int h = blockIdx.x >> 4;
    int q0 = ((blockIdx.x >> 2) & 3) * 64, k0 = (blockIdx.x & 3) * 64;
#pragma unroll
    for (int i = 0; i < 4; i++) {
        int id = i * 256 + t;
        int r = id >> 4, cb = id & 15;
        f32x4 val = *reinterpret_cast<const f32x4*>(&bias3[h * NN + (q0 + r) * 256 + k0 + cb * 4]);
        *reinterpret_cast<f32x4*>(&T[r][cb * 4]) = val;
    }
    __syncthreads();
#pragma unroll
    for (int i = 0; i < 4; i++) {
        int id = i * 256 + t;
        int kr = id >> 4, qb = id & 15;
        f32x4 o;
#pragma unroll
        for (int j = 0; j < 4; j++) o[j] = T[qb * 4 + j][kr];
        *reinterpret_cast<f32x4*>(&bias2[h * NN + (k0 + kr) * 256 + q0 + qb * 4]) = o;
    }
}

// ---------- fused QKVG projection + flash attention per (b,h), 8-wave blocks ----------
// 512 threads / 8 waves: each wave owns 32 rows (proj: 32 K,V,Q,G rows; attn: 32 q).
// Single fused 4-accumulator projection loop (64 acc VGPRs) -> fits 128-reg budget.
// XCD swizzle: 4 h-blocks of same b share id%8 -> same XCD -> z L2-hits.
__global__ __launch_bounds__(512, 4) void fat_kernel(const bf16_t* __restrict__ zF,
                                                     const bf16_t* __restrict__ wf,
                                                     const float* __restrict__ bias2,
                                                     bf16_t* __restrict__ om2,
                                                     bf16_t* __restrict__ gm2) {
    __shared__ bf16_t Kh[256][44];   // [key][c] padded -> conflict-free b128
    __shared__ bf16_t Vt[32][268];   // [c][key] padded -> 2-way b64 (free)
    int t = threadIdx.x;
    int id = blockIdx.x;
    int h = (id >> 3) & 3;
    int b = (id & 7) + (id >> 5) * 8;
    int w = t >> 6, lane = t & 63;
    int rsel = lane & 31, hi = lane >> 5;
    int hi8 = hi * 8, hi4 = hi * 4;
    bool lo = (hi == 0);
    const float SCL2 = 0.17677669529663687f * 1.4426950408889634f;  // scale * log2(e)
    const bf16_t* zg0 = zF + (size_t)(b * 8 + w) * 4096;  // this wave's 32-row group
    int fro = rsel * 16 + hi8;

    // ---- fused Q,K,V,G projection (swapped MFMA, C[c,row]), 32 rows/wave ----
    bf16x8 qf0, qf1;
    {
        const bf16_t* wq = wf + (size_t)(0 * 4 + h) * 4096;
        const bf16_t* wk = wf + (size_t)(1 * 4 + h) * 4096;
        const bf16_t* wv = wf + (size_t)(2 * 4 + h) * 4096;
        const bf16_t* wg = wf + (size_t)(3 * 4 + h) * 4096;
        f32x16 aq, ak, av, ag;
#pragma unroll
        for (int i = 0; i < 16; i++) { aq[i] = 0.f; ak[i] = 0.f; av[i] = 0.f; ag[i] = 0.f; }
#pragma unroll
        for (int ks = 0; ks < 8; ks++) {
            int off = ks * 512 + fro;
            bf16x8 zb = *reinterpret_cast<const bf16x8*>(zg0 + off);
            bf16x8 fq = *reinterpret_cast<const bf16x8*>(wq + off);
            bf16x8 fk = *reinterpret_cast<const bf16x8*>(wk + off);
            bf16x8 fv = *reinterpret_cast<const bf16x8*>(wv + off);
            bf16x8 fg = *reinterpret_cast<const bf16x8*>(wg + off);
            aq = __builtin_amdgcn_mfma_f32_32x32x16_bf16(fq, zb, aq, 0, 0, 0);
            ak = __builtin_amdgcn_mfma_f32_32x32x16_bf16(fk, zb, ak, 0, 0, 0);
            av = __builtin_amdgcn_mfma_f32_32x32x16_bf16(fv, zb, av, 0, 0, 0);
            ag = __builtin_amdgcn_mfma_f32_32x32x16_bf16(fg, zb, ag, 0, 0, 0);
        }
        int key0 = w * 32 + rsel;
        // K -> LDS (packed b128 writes, attn A-frag layout)
        bf16x8 f0, f1;
        packX(ak, lo, f0, f1);
        *reinterpret_cast<bf16x8*>(&Kh[key0][hi8]) = f0;
        *reinterpret_cast<bf16x8*>(&Kh[key0][16 + hi8]) = f1;
        // V -> LDS transposed (scalar b16 stores, identity key order)
#pragma unroll
        for (int r = 0; r < 16; r++) {
            int c = (r & 3) + 8 * (r >> 2) + hi4;
            Vt[c][key0] = (bf16_t)av[r];
        }
        // G: sigmoid + store head-major
#pragma unroll
        for (int i = 0; i < 16; i++) ag[i] = 1.0f / (1.0f + __expf(-ag[i]));
        bf16_t* grow = gm2 + ((size_t)h * NN + b * 256 + key0) * 32;
        packX(ag, lo, f0, f1);
        *reinterpret_cast<bf16x8*>(grow + hi8) = f0;
        *reinterpret_cast<bf16x8*>(grow + 16 + hi8) = f1;
        // Q -> register B-frags
        packX(aq, lo, qf0, qf1);
    }
    __syncthreads();

    // ---- flash attention: 32 q-rows per wave ----
    {
        int qpos = w * 32 + rsel;
        const float* bq = bias2 + (size_t)h * NN + qpos;  // + key*256

        f32x16 of;
#pragma unroll
        for (int i = 0; i < 16; i++) of[i] = 0.f;
        float m = -1e30f, l = 0.f;

        float bv[16];
#pragma unroll
        for (int e = 0; e < 16; e++) {
            int key = 8 * (e >> 2) + hi4 + (e & 3);
            bv[e] = bq[(size_t)key * 256];
        }
#pragma unroll
        for (int kt = 0; kt < 8; kt++) {
            bf16x8 k0 = *reinterpret_cast<bf16x8*>(&Kh[kt * 32 + rsel][hi8]);
            bf16x8 k1 = *reinterpret_cast<bf16x8*>(&Kh[kt * 32 + rsel][16 + hi8]);
            f32x16 s;
#pragma unroll
            for (int i = 0; i < 16; i++) s[i] = 0.f;
            __builtin_amdgcn_s_setprio(1);
            s = __builtin_amdgcn_mfma_f32_32x32x16_bf16(k0, qf0, s, 0, 0, 0);
            s = __builtin_amdgcn_mfma_f32_32x32x16_bf16(k1, qf1, s, 0, 0, 0);
            __builtin_amdgcn_s_setprio(0);
            // prefetch next chunk's bias
            float bvn[16];
            if (kt < 7) {
#pragma unroll
                for (int e = 0; e < 16; e++) {
                    int key = (kt + 1) * 32 + 8 * (e >> 2) + hi4 + (e & 3);
                    bvn[e] = bq[(size_t)key * 256];
                }
            }
            float tm[8];
#pragma unroll
            for (int e = 0; e < 16; e++) s[e] = s[e] * SCL2 + bv[e];
#pragma unroll
            for (int e = 0; e < 8; e++) tm[e] = fmaxf(s[e], s[e + 8]);
#pragma unroll
            for (int st = 4; st >= 1; st >>= 1)
#pragma unroll
                for (int e = 0; e < st; e++) tm[e] = fmaxf(tm[e], tm[e + st]);
            float pm = fmaxf(tm[0], __shfl_xor(tm[0], 32));
            // exact defer-max: rescale only if some lane's max grew
            if (__any(pm > m)) {
                float nm = fmaxf(m, pm);
                float al = __builtin_amdgcn_exp2f(m - nm);
                m = nm;
                l *= al;
#pragma unroll
                for (int i = 0; i < 16; i++) of[i] *= al;
            }
            float ts[8];
#pragma unroll
            for (int e = 0; e < 16; e++) s[e] = __builtin_amdgcn_exp2f(s[e] - m);
#pragma unroll
            for (int e = 0; e < 8; e++) ts[e] = s[e] + s[e + 8];
#pragma unroll
            for (int st = 4; st >= 1; st >>= 1)
#pragma unroll
                for (int e = 0; e < st; e++) ts[e] += ts[e + st];
            l += ts[0];
            // P fragments in native C-layout key order (no cross-lane pack)
            bf16x8 pf0 = frag4(pk2(s[0], s[1]), pk2(s[2], s[3]),
                               pk2(s[4], s[5]), pk2(s[6], s[7]));
            bf16x8 pf1 = frag4(pk2(s[8], s[9]), pk2(s[10], s[11]),
                               pk2(s[12], s[13]), pk2(s[14], s[15]));
            // V fragments with the SAME key order: paired b64 reads
            bf16x8 va = cat44(*reinterpret_cast<bf16x4*>(&Vt[rsel][kt * 32 + hi4]),
                              *reinterpret_cast<bf16x4*>(&Vt[rsel][kt * 32 + 8 + hi4]));
            bf16x8 vb = cat44(*reinterpret_cast<bf16x4*>(&Vt[rsel][kt * 32 + 16 + hi4]),
                              *reinterpret_cast<bf16x4*>(&Vt[rsel][kt * 32 + 24 + hi4]));
            __builtin_amdgcn_s_setprio(1);
            of = __builtin_amdgcn_mfma_f32_32x32x16_bf16(va, pf0, of, 0, 0, 0);
            of = __builtin_amdgcn_mfma_f32_32x32x16_bf16(vb, pf1, of, 0, 0, 0);
            __builtin_amdgcn_s_setprio(0);
            if (kt < 7) {
#pragma unroll
                for (int e = 0; e < 16; e++) bv[e] = bvn[e];
            }
        }

        l += __shfl_xor(l, 32);
        float linv = 1.0f / l;
#pragma unroll
        for (int i = 0; i < 16; i++) of[i] *= linv;
        bf16x8 o0, o1;
        packX(of, lo, o0, o1);
        bf16_t* orow = om2 + ((size_t)h * NN + b * 256 + qpos) * 32;
        *reinterpret_cast<bf16x8*>(orow + hi8) = o0;
        *reinterpret_cast<bf16x8*>(orow + 16 + hi8) = o1;
    }
}

// ---------------- final: out = (o*g) @ Wo, fp32 out, LDS-staged epilogue ----------
__global__ __launch_bounds__(256) void final_kernel(const bf16_t* __restrict__ om2,
                                                    const bf16_t* __restrict__ gm2,
                                                    const bf16_t* __restrict__ wfO,
                                                    float* __restrict__ out) {
    __shared__ __align__(16) char smraw[64 * 136 * 2];
    bf16_t(*As)[136] = reinterpret_cast<bf16_t(*)[136]>(smraw);
    float(*Of)[68] = reinterpret_cast<float(*)[68]>(smraw);
    int t = threadIdx.x;
    int rb = blockIdx.x;
#pragma unroll
    for (int i = 0; i < 4; i++) {
        int c = i * 256 + t;
        int r = c >> 4, off = (c & 15) * 8;
        size_t hm = ((size_t)(off >> 5) * NN + rb * 64 + r) * 32 + (off & 31);
        bf16x8 o8 = *reinterpret_cast<const bf16x8*>(&om2[hm]);
        bf16x8 g8 = *reinterpret_cast<const bf16x8*>(&gm2[hm]);
        bf16x8 p8;
#pragma unroll
        for (int e = 0; e < 8; e++) p8[e] = (bf16_t)((float)o8[e] * (float)g8[e]);
        *reinterpret_cast<bf16x8*>(&As[r][off]) = p8;
    }
    __syncthreads();
    int w = t >> 6, lane = t & 63;
    int lx = lane & 15, ly = lane >> 4;
    int m0 = (w >> 1) * 32, n0 = (w & 1) * 32;
    bf16x8 af[2][4];
#pragma unroll
    for (int mt = 0; mt < 2; mt++)
#pragma unroll
        for (int ks = 0; ks < 4; ks++)
            af[mt][ks] = *reinterpret_cast<bf16x8*>(&As[m0 + mt * 16 + lx][ks * 32 + ly * 8]);
    __syncthreads();  // As dead; Of may alias

    for (int half = 0; half < 2; half++) {
        int nc0 = half * 64;
        bf16x8 bfr[2][4];
#pragma unroll
        for (int nt = 0; nt < 2; nt++) {
            int oc = ((nc0 + n0) >> 4) + nt;
#pragma unroll
            for (int ks = 0; ks < 4; ks++)
                bfr[nt][ks] = *reinterpret_cast<const bf16x8*>(
                    &wfO[oc * 2048 + ks * 512 + lx * 32 + ly * 8]);
        }
        f32x4 acc[2][2];
#pragma unroll
        for (int mt = 0; mt < 2; mt++)
#pragma unroll
            for (int nt = 0; nt < 2; nt++) acc[mt][nt] = (f32x4){0.f, 0.f, 0.f, 0.f};
#pragma unroll
        for (int ks = 0; ks < 4; ks++)
#pragma unroll
            for (int mt = 0; mt < 2; mt++)
#pragma unroll
                for (int nt = 0; nt < 2; nt++)
                    acc[mt][nt] = __builtin_amdgcn_mfma_f32_16x16x32_bf16(af[mt][ks], bfr[nt][ks], acc[mt][nt], 0, 0, 0);
#pragma unroll
        for (int mt = 0; mt < 2; mt++)
#pragma unroll
            for (int nt = 0; nt < 2; nt++)
#pragma unroll
                for (int r = 0; r < 4; r++)
                    Of[m0 + mt * 16 + ly * 4 + r][n0 + nt * 16 + lx] = acc[mt][nt][r];
        __syncthreads();
#pragma unroll
        for (int j = 0; j < 4; j++) {
            int ch = j * 256 + t;
            int r = ch >> 4, cb = ch & 15;
            f32x4 val = *reinterpret_cast<f32x4*>(&Of[r][cb * 4]);
            *reinterpret_cast<f32x4*>(&out[(rb * 64 + r) * 128 + nc0 + cb * 4]) = val;
        }
        __syncthreads();
    }
}

extern "C" void kernel_launch(void* const* d_in, const int* in_sizes, int n_in,
                              void* d_out, int out_size, void* d_ws, size_t ws_size,
                              hipStream_t stream) {
    const float* x   = (const float*)d_in[0];
    const float* lnw = (const float*)d_in[1];
    const float* lnb = (const float*)d_in[2];
    const float* Wb  = (const float*)d_in[3];
    const float* Wq  = (const float*)d_in[4];
    const float* Wk  = (const float*)d_in[5];
    const float* Wv  = (const float*)d_in[6];
    const float* Wg  = (const float*)d_in[7];
    const float* Wo  = (const float*)d_in[8];
    float* out = (float*)d_out;

    char* ws = (char*)d_ws;
    const size_t MAT = (size_t)NN * 128 * sizeof(bf16_t);  // 16 MB
    bf16_t* zF    = (bf16_t*)(ws);                           // fragment-ready z
    bf16_t* gmat  = (bf16_t*)(ws + MAT);                     // head-major
    bf16_t* omat  = (bf16_t*)(ws + 2 * MAT);                 // head-major
    bf16_t* wf    = (bf16_t*)(ws + 3 * MAT);                 // 16*4096 bf16 = 128KB
    bf16_t* wfO   = (bf16_t*)(ws + 3 * MAT + (128 << 10));   // 8*2048 bf16 = 32KB
    float*  bias3 = (float*)(ws + 3 * MAT + (1 << 20));      // 1MB
    float*  bias2 = (float*)(ws + 3 * MAT + (2 << 20));      // 1MB

    convw_kernel<<<24, 256, 0, stream>>>(Wq, Wk, Wv, Wg, Wo, wf, wfO);
    ln_kernel<<<2048, 256, 0, stream>>>(x, lnw, lnb, Wb, zF, bias3);
    biastr_kernel<<<64, 256, 0, stream>>>(bias3, bias2);
    fat_kernel<<<1024, 512, 0, stream>>>(zF, wf, bias2, omat, gmat);
    final_kernel<<<1024, 256, 0, stream>>>(omat, gmat, wfO, out);
}

// Round 14
// 76.130 us; speedup vs baseline: 1.6095x; 1.0236x over previous
//
#include <hip/hip_runtime.h>
#include <hip/hip_bf16.h>

#define NN 65536   // N*N rows
#define DD 128
#define NH 4
#define HDIM 32

typedef __bf16 bf16_t;
typedef __bf16 bf16x8 __attribute__((ext_vector_type(8)));
typedef __bf16 bf16x4 __attribute__((ext_vector_type(4)));
typedef __bf16 bf16x2 __attribute__((ext_vector_type(2)));
typedef float f32x4 __attribute__((ext_vector_type(4)));
typedef float f32x16 __attribute__((ext_vector_type(16)));
typedef unsigned int u32;
typedef unsigned int u32x4 __attribute__((ext_vector_type(4)));

__device__ inline u32 pk2(float a, float b) {
    bf16x2 t;
    t[0] = (bf16_t)a;
    t[1] = (bf16_t)b;
    return __builtin_bit_cast(u32, t);
}
__device__ inline bf16x8 frag4(u32 a, u32 b, u32 c, u32 d) {
    u32x4 t = {a, b, c, d};
    return __builtin_bit_cast(bf16x8, t);
}
__device__ inline bf16x8 cat44(bf16x4 a, bf16x4 b) {
    bf16x8 r;
#pragma unroll
    for (int j = 0; j < 4; j++) { r[j] = a[j]; r[4 + j] = b[j]; }
    return r;
}
// VERIFIED (R2-R6): pack C-layout (col=lane&31, c=(r&3)+8*(r>>2)+4*hi) into two
// contiguous frags via shfl. f0 = lane's c[hi*8..+8), f1 = c[16+hi*8..+8).
__device__ inline void packX(const f32x16& s, bool lo, bf16x8& f0, bf16x8& f1) {
    u32 wv[8];
#pragma unroll
    for (int g = 0; g < 4; g++) {
        wv[2 * g] = pk2(s[4 * g], s[4 * g + 1]);
        wv[2 * g + 1] = pk2(s[4 * g + 2], s[4 * g + 3]);
    }
    u32 p0 = __shfl_xor(wv[0], 32), p1 = __shfl_xor(wv[1], 32);
    u32 p2 = __shfl_xor(wv[2], 32), p3 = __shfl_xor(wv[3], 32);
    u32 p4 = __shfl_xor(wv[4], 32), p5 = __shfl_xor(wv[5], 32);
    u32 p6 = __shfl_xor(wv[6], 32), p7 = __shfl_xor(wv[7], 32);
    f0 = frag4(lo ? wv[0] : p2, lo ? wv[1] : p3, lo ? p0 : wv[2], lo ? p1 : wv[3]);
    f1 = frag4(lo ? wv[4] : p6, lo ? wv[5] : p7, lo ? p4 : wv[6], lo ? p5 : wv[7]);
}

// ------------- weight conversion to fragment-ready layouts (coalesced reads in hot kernels)
__global__ __launch_bounds__(256) void convw_kernel(const float* __restrict__ Wq,
                                                    const float* __restrict__ Wk,
                                                    const float* __restrict__ Wv,
                                                    const float* __restrict__ Wg,
                                                    const float* __restrict__ Wo,
                                                    bf16_t* __restrict__ wf,
                                                    bf16_t* __restrict__ wfO) {
    __shared__ float Ws[128][33];
    __shared__ float Ws2[128][17];
    int blk = blockIdx.x, t = threadIdx.x;
    if (blk < 16) {
        int m = blk >> 2, h = blk & 3;
        const float* W = (m == 0) ? Wq : (m == 1) ? Wk : (m == 2) ? Wv : Wg;
#pragma unroll
        for (int p = 0; p < 16; p++) {
            int d = p * 8 + (t >> 5), o = t & 31;
            Ws[d][o] = W[d * 128 + h * 32 + o];
        }
        __syncthreads();
        bf16_t* dst = wf + (size_t)blk * 4096;
#pragma unroll
        for (int p = 0; p < 16; p++) {
            int j = p * 256 + t;
            int ks = j >> 9, rsel = (j >> 4) & 31, e = j & 15;
            dst[j] = (bf16_t)Ws[ks * 16 + e][rsel];
        }
    } else {
        int oc = blk - 16;  // 0..7
#pragma unroll
        for (int p = 0; p < 8; p++) {
            int d = p * 16 + (t >> 4), o = t & 15;
            Ws2[d][o] = Wo[d * 128 + oc * 16 + o];
        }
        __syncthreads();
        bf16_t* dst = wfO + (size_t)oc * 2048;
#pragma unroll
        for (int p = 0; p < 8; p++) {
            int j = p * 256 + t;
            int ks = j >> 9, rem = j & 511;
            int lx = rem >> 5, ly = (rem >> 3) & 3, e = j & 7;
            dst[j] = (bf16_t)Ws2[ks * 32 + ly * 8 + e][lx];
        }
    }
}

// ---------------- LayerNorm + bias; z emitted in fragment-ready zF layout ----------------
__global__ __launch_bounds__(256) void ln_kernel(const float* __restrict__ x,
                                                 const float* __restrict__ lw,
                                                 const float* __restrict__ lb,
                                                 const float* __restrict__ Wb,
                                                 bf16_t* __restrict__ zF,
                                                 float* __restrict__ bias3) {
    __shared__ bf16_t zs[4096];        // [ks][rsel][16], 8KB
    __shared__ float bias_s[4][32];
    int t = threadIdx.x;
    int g = t >> 5, l32 = t & 31;
    int rowbase = blockIdx.x * 32;
    int d0 = l32 * 4;
    f32x4 lwv = *reinterpret_cast<const f32x4*>(&lw[d0]);
    f32x4 lbv = *reinterpret_cast<const f32x4*>(&lb[d0]);
    f32x4 wbj[4];
#pragma unroll
    for (int j = 0; j < 4; j++) wbj[j] = *reinterpret_cast<const f32x4*>(&Wb[(d0 + j) * 4]);
#pragma unroll
    for (int r4 = 0; r4 < 4; r4++) {
        int roff = r4 * 8 + g;
        int row = rowbase + roff;
        f32x4 v = *reinterpret_cast<const f32x4*>(&x[(size_t)row * 128 + d0]);
        float s1 = v[0] + v[1] + v[2] + v[3];
        float s2 = v[0] * v[0] + v[1] * v[1] + v[2] * v[2] + v[3] * v[3];
#pragma unroll
        for (int m = 1; m < 32; m <<= 1) {
            s1 += __shfl_xor(s1, m);
            s2 += __shfl_xor(s2, m);
        }
        float mu = s1 * (1.0f / 128.0f);
        float var = s2 * (1.0f / 128.0f) - mu * mu;
        float rs = rsqrtf(var + 1e-5f);
        float zv[4];
        bf16x4 pk;
#pragma unroll
        for (int j = 0; j < 4; j++) {
            zv[j] = (v[j] - mu) * rs * lwv[j] + lbv[j];
            pk[j] = (bf16_t)zv[j];
        }
        *reinterpret_cast<bf16x4*>(&zs[(l32 >> 2) * 512 + roff * 16 + (l32 & 3) * 4]) = pk;
        f32x4 pb = {0.f, 0.f, 0.f, 0.f};
#pragma unroll
        for (int j = 0; j < 4; j++)
#pragma unroll
            for (int hh = 0; hh < 4; hh++) pb[hh] += zv[j] * wbj[j][hh];
#pragma unroll
        for (int m = 1; m < 32; m <<= 1) {
#pragma unroll
            for (int hh = 0; hh < 4; hh++) pb[hh] += __shfl_xor(pb[hh], m);
        }
        if (l32 == 0) {
#pragma unroll
            for (int hh = 0; hh < 4; hh++)
                bias_s[hh][roff] = pb[hh] * 1.4426950408889634f;
        }
    }
    __syncthreads();
    if (t < 128) {
        bias3[(size_t)(t >> 5) * NN + rowbase + (t & 31)] = bias_s[t >> 5][t & 31];
    }
    bf16_t* dst = zF + (size_t)blockIdx.x * 4096;
#pragma unroll
    for (int p = 0; p < 2; p++) {
        int c = p * 2048 + t * 8;
        *reinterpret_cast<bf16x8*>(dst + c) = *reinterpret_cast<bf16x8*>(zs + c);
    }
}

// ---------------- bias transpose: bias2[h][k][q] = bias3[h][q*256+k] ----------------
__global__ __launch_bounds__(256) void biastr_kernel(const float* __restrict__ bias3,
                                                     float* __restrict__ bias2) {
    __shared__ float T[64][68];
    int t = threadIdx.x;
    int h = blockIdx.x >> 4;
    int q0 = ((blockIdx.x >> 2) & 3) * 64, k0 = (blockIdx.x & 3) * 64;
#pragma unroll
    for (int i = 0; i < 4; i++) {
        int id = i * 256 + t;
        int r = id >> 4, cb = id & 15;
        f32x4 val = *reinterpret_cast<const f32x4*>(&bias3[h * NN + (q0 + r) * 256 + k0 + cb * 4]);
        *reinterpret_cast<f32x4*>(&T[r][cb * 4]) = val;
    }
    __syncthreads();
#pragma unroll
    for (int i = 0; i < 4; i++) {
        int id = i * 256 + t;
        int kr = id >> 4, qb = id & 15;
        f32x4 o;
#pragma unroll
        for (int j = 0; j < 4; j++) o[j] = T[qb * 4 + j][kr];
        *reinterpret_cast<f32x4*>(&bias2[h * NN + (k0 + kr) * 256 + q0 + qb * 4]) = o;
    }
}

// ---------- fused QKVG projection + flash attention per (b,h), 8-wave blocks ----------
// Bias folded into QK^T as MFMA C-init (bv load order == C-layout slot order);
// Q pre-scaled by SCL2 in f32; g consumed in-register (never stored).
__global__ __launch_bounds__(512, 4) void fat_kernel(const bf16_t* __restrict__ zF,
                                                     const bf16_t* __restrict__ wf,
                                                     const float* __restrict__ bias2,
                                                     bf16_t* __restrict__ om2) {
    __shared__ bf16_t Kh[256][44];   // [key][c] padded -> conflict-free b128
    __shared__ bf16_t Vt[32][268];   // [c][key] padded -> 2-way b64 (free)
    int t = threadIdx.x;
    int id = blockIdx.x;
    int h = (id >> 3) & 3;
    int b = (id & 7) + (id >> 5) * 8;
    int w = t >> 6, lane = t & 63;
    int rsel = lane & 31, hi = lane >> 5;
    int hi8 = hi * 8, hi4 = hi * 4;
    bool lo = (hi == 0);
    const float SCL2 = 0.17677669529663687f * 1.4426950408889634f;  // scale * log2(e)
    const bf16_t* zg0 = zF + (size_t)(b * 8 + w) * 4096;  // this wave's 32-row group
    int fro = rsel * 16 + hi8;
    int qpos = w * 32 + rsel;
    const float* bq = bias2 + (size_t)h * NN + qpos;  // + key*256

    // hoist chunk-0 bias load (hides L2 latency under projection)
    f32x16 bv;
#pragma unroll
    for (int e = 0; e < 16; e++) {
        int key = 8 * (e >> 2) + hi4 + (e & 3);
        bv[e] = bq[(size_t)key * 256];
    }

    // ---- fused Q,K,V,G projection (swapped MFMA, C[c,row]), 32 rows/wave ----
    bf16x8 qf0, qf1;
    f32x16 sg;   // sigmoid(g) kept in-register through attention
    {
        const bf16_t* wq = wf + (size_t)(0 * 4 + h) * 4096;
        const bf16_t* wk = wf + (size_t)(1 * 4 + h) * 4096;
        const bf16_t* wv = wf + (size_t)(2 * 4 + h) * 4096;
        const bf16_t* wg = wf + (size_t)(3 * 4 + h) * 4096;
        f32x16 aq, ak, av, ag;
#pragma unroll
        for (int i = 0; i < 16; i++) { aq[i] = 0.f; ak[i] = 0.f; av[i] = 0.f; ag[i] = 0.f; }
#pragma unroll
        for (int ks = 0; ks < 8; ks++) {
            int off = ks * 512 + fro;
            bf16x8 zb = *reinterpret_cast<const bf16x8*>(zg0 + off);
            bf16x8 fq = *reinterpret_cast<const bf16x8*>(wq + off);
            bf16x8 fk = *reinterpret_cast<const bf16x8*>(wk + off);
            bf16x8 fv = *reinterpret_cast<const bf16x8*>(wv + off);
            bf16x8 fg = *reinterpret_cast<const bf16x8*>(wg + off);
            aq = __builtin_amdgcn_mfma_f32_32x32x16_bf16(fq, zb, aq, 0, 0, 0);
            ak = __builtin_amdgcn_mfma_f32_32x32x16_bf16(fk, zb, ak, 0, 0, 0);
            av = __builtin_amdgcn_mfma_f32_32x32x16_bf16(fv, zb, av, 0, 0, 0);
            ag = __builtin_amdgcn_mfma_f32_32x32x16_bf16(fg, zb, ag, 0, 0, 0);
        }
        int key0 = w * 32 + rsel;
        // K -> LDS (packed b128 writes, attn A-frag layout)
        bf16x8 f0, f1;
        packX(ak, lo, f0, f1);
        *reinterpret_cast<bf16x8*>(&Kh[key0][hi8]) = f0;
        *reinterpret_cast<bf16x8*>(&Kh[key0][16 + hi8]) = f1;
        // V -> LDS transposed (scalar b16 stores, identity key order)
#pragma unroll
        for (int r = 0; r < 16; r++) {
            int c = (r & 3) + 8 * (r >> 2) + hi4;
            Vt[c][key0] = (bf16_t)av[r];
        }
        // G: sigmoid, kept in registers (C-layout matches of's layout)
#pragma unroll
        for (int i = 0; i < 16; i++) sg[i] = 1.0f / (1.0f + __expf(-ag[i]));
        // Q: fold SCL2 into Q (f32, before bf16 pack), then pack to B-frags
#pragma unroll
        for (int i = 0; i < 16; i++) aq[i] *= SCL2;
        packX(aq, lo, qf0, qf1);
    }
    __syncthreads();

    // ---- flash attention: 32 q-rows per wave; s init = bias (C-layout) ----
    {
        f32x16 of;
#pragma unroll
        for (int i = 0; i < 16; i++) of[i] = 0.f;
        float m = -1e30f, l = 0.f;

#pragma unroll
        for (int kt = 0; kt < 8; kt++) {
            bf16x8 k0 = *reinterpret_cast<bf16x8*>(&Kh[kt * 32 + rsel][hi8]);
            bf16x8 k1 = *reinterpret_cast<bf16x8*>(&Kh[kt * 32 + rsel][16 + hi8]);
            f32x16 s = bv;  // bias as C-init: s = qk*SCL2 + bias after the 2 MFMAs
            __builtin_amdgcn_s_setprio(1);
            s = __builtin_amdgcn_mfma_f32_32x32x16_bf16(k0, qf0, s, 0, 0, 0);
            s = __builtin_amdgcn_mfma_f32_32x32x16_bf16(k1, qf1, s, 0, 0, 0);
            __builtin_amdgcn_s_setprio(0);
            // prefetch next chunk's bias
            if (kt < 7) {
#pragma unroll
                for (int e = 0; e < 16; e++) {
                    int key = (kt + 1) * 32 + 8 * (e >> 2) + hi4 + (e & 3);
                    bv[e] = bq[(size_t)key * 256];
                }
            }
            // row max via max3-friendly triples: 16 -> 6 -> 2 -> 1
            float t0 = fmaxf(fmaxf(s[0], s[1]), s[2]);
            float t1 = fmaxf(fmaxf(s[3], s[4]), s[5]);
            float t2 = fmaxf(fmaxf(s[6], s[7]), s[8]);
            float t3 = fmaxf(fmaxf(s[9], s[10]), s[11]);
            float t4 = fmaxf(fmaxf(s[12], s[13]), s[14]);
            float u0 = fmaxf(fmaxf(t0, t1), s[15]);
            float u1 = fmaxf(fmaxf(t2, t3), t4);
            float pm = fmaxf(u0, u1);
            pm = fmaxf(pm, __shfl_xor(pm, 32));
            // exact defer-max: rescale only if some lane's max grew
            if (__any(pm > m)) {
                float nm = fmaxf(m, pm);
                float al = __builtin_amdgcn_exp2f(m - nm);
                m = nm;
                l *= al;
#pragma unroll
                for (int i = 0; i < 16; i++) of[i] *= al;
            }
            float ts[8];
#pragma unroll
            for (int e = 0; e < 16; e++) s[e] = __builtin_amdgcn_exp2f(s[e] - m);
#pragma unroll
            for (int e = 0; e < 8; e++) ts[e] = s[e] + s[e + 8];
#pragma unroll
            for (int st = 4; st >= 1; st >>= 1)
#pragma unroll
                for (int e = 0; e < st; e++) ts[e] += ts[e + st];
            l += ts[0];
            // P fragments in native C-layout key order (no cross-lane pack)
            bf16x8 pf0 = frag4(pk2(s[0], s[1]), pk2(s[2], s[3]),
                               pk2(s[4], s[5]), pk2(s[6], s[7]));
            bf16x8 pf1 = frag4(pk2(s[8], s[9]), pk2(s[10], s[11]),
                               pk2(s[12], s[13]), pk2(s[14], s[15]));
            // V fragments with the SAME key order: paired b64 reads
            bf16x8 va = cat44(*reinterpret_cast<bf16x4*>(&Vt[rsel][kt * 32 + hi4]),
                              *reinterpret_cast<bf16x4*>(&Vt[rsel][kt * 32 + 8 + hi4]));
            bf16x8 vb = cat44(*reinterpret_cast<bf16x4*>(&Vt[rsel][kt * 32 + 16 + hi4]),
                              *reinterpret_cast<bf16x4*>(&Vt[rsel][kt * 32 + 24 + hi4]));
            __builtin_amdgcn_s_setprio(1);
            of = __builtin_amdgcn_mfma_f32_32x32x16_bf16(va, pf0, of, 0, 0, 0);
            of = __builtin_amdgcn_mfma_f32_32x32x16_bf16(vb, pf1, of, 0, 0, 0);
            __builtin_amdgcn_s_setprio(0);
        }

        l += __shfl_xor(l, 32);
        float linv = 1.0f / l;
        // in-register gating: o * g (same C-layout), then pack+store once
#pragma unroll
        for (int i = 0; i < 16; i++) of[i] = of[i] * linv * sg[i];
        bf16x8 o0, o1;
        packX(of, lo, o0, o1);
        bf16_t* orow = om2 + ((size_t)h * NN + b * 256 + qpos) * 32;
        *reinterpret_cast<bf16x8*>(orow + hi8) = o0;
        *reinterpret_cast<bf16x8*>(orow + 16 + hi8) = o1;
    }
}

// ---------------- final: out = om @ Wo (om pre-gated), fp32 out ----------
__global__ __launch_bounds__(256) void final_kernel(const bf16_t* __restrict__ om2,
                                                    const bf16_t* __restrict__ wfO,
                                                    float* __restrict__ out) {
    __shared__ __align__(16) char smraw[64 * 136 * 2];
    bf16_t(*As)[136] = reinterpret_cast<bf16_t(*)[136]>(smraw);
    float(*Of)[68] = reinterpret_cast<float(*)[68]>(smraw);
    int t = threadIdx.x;
    int rb = blockIdx.x;
#pragma unroll
    for (int i = 0; i < 4; i++) {
        int c = i * 256 + t;
        int r = c >> 4, off = (c & 15) * 8;
        size_t hm = ((size_t)(off >> 5) * NN + rb * 64 + r) * 32 + (off & 31);
        bf16x8 o8 = *reinterpret_cast<const bf16x8*>(&om2[hm]);
        *reinterpret_cast<bf16x8*>(&As[r][off]) = o8;
    }
    __syncthreads();
    int w = t >> 6, lane = t & 63;
    int lx = lane & 15, ly = lane >> 4;
    int m0 = (w >> 1) * 32, n0 = (w & 1) * 32;
    bf16x8 af[2][4];
#pragma unroll
    for (int mt = 0; mt < 2; mt++)
#pragma unroll
        for (int ks = 0; ks < 4; ks++)
            af[mt][ks] = *reinterpret_cast<bf16x8*>(&As[m0 + mt * 16 + lx][ks * 32 + ly * 8]);
    __syncthreads();  // As dead; Of may alias

    for (int half = 0; half < 2; half++) {
        int nc0 = half * 64;
        bf16x8 bfr[2][4];
#pragma unroll
        for (int nt = 0; nt < 2; nt++) {
            int oc = ((nc0 + n0) >> 4) + nt;
#pragma unroll
            for (int ks = 0; ks < 4; ks++)
                bfr[nt][ks] = *reinterpret_cast<const bf16x8*>(
                    &wfO[oc * 2048 + ks * 512 + lx * 32 + ly * 8]);
        }
        f32x4 acc[2][2];
#pragma unroll
        for (int mt = 0; mt < 2; mt++)
#pragma unroll
            for (int nt = 0; nt < 2; nt++) acc[mt][nt] = (f32x4){0.f, 0.f, 0.f, 0.f};
#pragma unroll
        for (int ks = 0; ks < 4; ks++)
#pragma unroll
            for (int mt = 0; mt < 2; mt++)
#pragma unroll
                for (int nt = 0; nt < 2; nt++)
                    acc[mt][nt] = __builtin_amdgcn_mfma_f32_16x16x32_bf16(af[mt][ks], bfr[nt][ks], acc[mt][nt], 0, 0, 0);
#pragma unroll
        for (int mt = 0; mt < 2; mt++)
#pragma unroll
            for (int nt = 0; nt < 2; nt++)
#pragma unroll
                for (int r = 0; r < 4; r++)
                    Of[m0 + mt * 16 + ly * 4 + r][n0 + nt * 16 + lx] = acc[mt][nt][r];
        __syncthreads();
#pragma unroll
        for (int j = 0; j < 4; j++) {
            int ch = j * 256 + t;
            int r = ch >> 4, cb = ch & 15;
            f32x4 val = *reinterpret_cast<f32x4*>(&Of[r][cb * 4]);
            *reinterpret_cast<f32x4*>(&out[(rb * 64 + r) * 128 + nc0 + cb * 4]) = val;
        }
        __syncthreads();
    }
}

extern "C" void kernel_launch(void* const* d_in, const int* in_sizes, int n_in,
                              void* d_out, int out_size, void* d_ws, size_t ws_size,
                              hipStream_t stream) {
    const float* x   = (const float*)d_in[0];
    const float* lnw = (const float*)d_in[1];
    const float* lnb = (const float*)d_in[2];
    const float* Wb  = (const float*)d_in[3];
    const float* Wq  = (const float*)d_in[4];
    const float* Wk  = (const float*)d_in[5];
    const float* Wv  = (const float*)d_in[6];
    const float* Wg  = (const float*)d_in[7];
    const float* Wo  = (const float*)d_in[8];
    float* out = (float*)d_out;

    char* ws = (char*)d_ws;
    const size_t MAT = (size_t)NN * 128 * sizeof(bf16_t);  // 16 MB
    bf16_t* zF    = (bf16_t*)(ws);                           // fragment-ready z
    bf16_t* omat  = (bf16_t*)(ws + MAT);                     // head-major, pre-gated
    bf16_t* wf    = (bf16_t*)(ws + 2 * MAT);                 // 16*4096 bf16 = 128KB
    bf16_t* wfO   = (bf16_t*)(ws + 2 * MAT + (128 << 10));   // 8*2048 bf16 = 32KB
    float*  bias3 = (float*)(ws + 2 * MAT + (1 << 20));      // 1MB
    float*  bias2 = (float*)(ws + 2 * MAT + (2 << 20));      // 1MB

    convw_kernel<<<24, 256, 0, stream>>>(Wq, Wk, Wv, Wg, Wo, wf, wfO);
    ln_kernel<<<2048, 256, 0, stream>>>(x, lnw, lnb, Wb, zF, bias3);
    biastr_kernel<<<64, 256, 0, stream>>>(bias3, bias2);
    fat_kernel<<<1024, 512, 0, stream>>>(zF, wf, bias2, omat);
    final_kernel<<<1024, 256, 0, stream>>>(omat, wfO, out);
}

// Round 15
// 74.849 us; speedup vs baseline: 1.6370x; 1.0171x over previous
//
#include <hip/hip_runtime.h>
#include <hip/hip_bf16.h>

#define NN 65536   // N*N rows
#define DD 128
#define NH 4
#define HDIM 32

typedef __bf16 bf16_t;
typedef __bf16 bf16x8 __attribute__((ext_vector_type(8)));
typedef __bf16 bf16x4 __attribute__((ext_vector_type(4)));
typedef __bf16 bf16x2 __attribute__((ext_vector_type(2)));
typedef float f32x4 __attribute__((ext_vector_type(4)));
typedef float f32x16 __attribute__((ext_vector_type(16)));
typedef unsigned int u32;
typedef unsigned int u32x4 __attribute__((ext_vector_type(4)));

__device__ inline u32 pk2(float a, float b) {
    bf16x2 t;
    t[0] = (bf16_t)a;
    t[1] = (bf16_t)b;
    return __builtin_bit_cast(u32, t);
}
__device__ inline bf16x8 frag4(u32 a, u32 b, u32 c, u32 d) {
    u32x4 t = {a, b, c, d};
    return __builtin_bit_cast(bf16x8, t);
}
__device__ inline bf16x8 cat44(bf16x4 a, bf16x4 b) {
    bf16x8 r;
#pragma unroll
    for (int j = 0; j < 4; j++) { r[j] = a[j]; r[4 + j] = b[j]; }
    return r;
}
// VERIFIED (R2-R6): pack C-layout (col=lane&31, c=(r&3)+8*(r>>2)+4*hi) into two
// contiguous frags via shfl. f0 = lane's c[hi*8..+8), f1 = c[16+hi*8..+8).
__device__ inline void packX(const f32x16& s, bool lo, bf16x8& f0, bf16x8& f1) {
    u32 wv[8];
#pragma unroll
    for (int g = 0; g < 4; g++) {
        wv[2 * g] = pk2(s[4 * g], s[4 * g + 1]);
        wv[2 * g + 1] = pk2(s[4 * g + 2], s[4 * g + 3]);
    }
    u32 p0 = __shfl_xor(wv[0], 32), p1 = __shfl_xor(wv[1], 32);
    u32 p2 = __shfl_xor(wv[2], 32), p3 = __shfl_xor(wv[3], 32);
    u32 p4 = __shfl_xor(wv[4], 32), p5 = __shfl_xor(wv[5], 32);
    u32 p6 = __shfl_xor(wv[6], 32), p7 = __shfl_xor(wv[7], 32);
    f0 = frag4(lo ? wv[0] : p2, lo ? wv[1] : p3, lo ? p0 : wv[2], lo ? p1 : wv[3]);
    f1 = frag4(lo ? wv[4] : p6, lo ? wv[5] : p7, lo ? p4 : wv[6], lo ? p5 : wv[7]);
}

// ------------- weight conversion to fragment-ready layouts (coalesced reads in hot kernels)
__global__ __launch_bounds__(256) void convw_kernel(const float* __restrict__ Wq,
                                                    const float* __restrict__ Wk,
                                                    const float* __restrict__ Wv,
                                                    const float* __restrict__ Wg,
                                                    const float* __restrict__ Wo,
                                                    bf16_t* __restrict__ wf,
                                                    bf16_t* __restrict__ wfO) {
    __shared__ float Ws[128][33];
    __shared__ float Ws2[128][17];
    int blk = blockIdx.x, t = threadIdx.x;
    if (blk < 16) {
        int m = blk >> 2, h = blk & 3;
        const float* W = (m == 0) ? Wq : (m == 1) ? Wk : (m == 2) ? Wv : Wg;
#pragma unroll
        for (int p = 0; p < 16; p++) {
            int d = p * 8 + (t >> 5), o = t & 31;
            Ws[d][o] = W[d * 128 + h * 32 + o];
        }
        __syncthreads();
        bf16_t* dst = wf + (size_t)blk * 4096;
#pragma unroll
        for (int p = 0; p < 16; p++) {
            int j = p * 256 + t;
            int ks = j >> 9, rsel = (j >> 4) & 31, e = j & 15;
            dst[j] = (bf16_t)Ws[ks * 16 + e][rsel];
        }
    } else {
        int oc = blk - 16;  // 0..7
#pragma unroll
        for (int p = 0; p < 8; p++) {
            int d = p * 16 + (t >> 4), o = t & 15;
            Ws2[d][o] = Wo[d * 128 + oc * 16 + o];
        }
        __syncthreads();
        bf16_t* dst = wfO + (size_t)oc * 2048;
#pragma unroll
        for (int p = 0; p < 8; p++) {
            int j = p * 256 + t;
            int ks = j >> 9, rem = j & 511;
            int lx = rem >> 5, ly = (rem >> 3) & 3, e = j & 7;
            dst[j] = (bf16_t)Ws2[ks * 32 + ly * 8 + e][lx];
        }
    }
}

// ---------------- LayerNorm + bias; z emitted in fragment-ready zF layout ----------------
__global__ __launch_bounds__(256) void ln_kernel(const float* __restrict__ x,
                                                 const float* __restrict__ lw,
                                                 const float* __restrict__ lb,
                                                 const float* __restrict__ Wb,
                                                 bf16_t* __restrict__ zF,
                                                 float* __restrict__ bias3) {
    __shared__ bf16_t zs[4096];        // [ks][rsel][16], 8KB
    __shared__ float bias_s[4][32];
    int t = threadIdx.x;
    int g = t >> 5, l32 = t & 31;
    int rowbase = blockIdx.x * 32;
    int d0 = l32 * 4;
    f32x4 lwv = *reinterpret_cast<const f32x4*>(&lw[d0]);
    f32x4 lbv = *reinterpret_cast<const f32x4*>(&lb[d0]);
    f32x4 wbj[4];
#pragma unroll
    for (int j = 0; j < 4; j++) wbj[j] = *reinterpret_cast<const f32x4*>(&Wb[(d0 + j) * 4]);
#pragma unroll
    for (int r4 = 0; r4 < 4; r4++) {
        int roff = r4 * 8 + g;
        int row = rowbase + roff;
        f32x4 v = *reinterpret_cast<const f32x4*>(&x[(size_t)row * 128 + d0]);
        float s1 = v[0] + v[1] + v[2] + v[3];
        float s2 = v[0] * v[0] + v[1] * v[1] + v[2] * v[2] + v[3] * v[3];
#pragma unroll
        for (int m = 1; m < 32; m <<= 1) {
            s1 += __shfl_xor(s1, m);
            s2 += __shfl_xor(s2, m);
        }
        float mu = s1 * (1.0f / 128.0f);
        float var = s2 * (1.0f / 128.0f) - mu * mu;
        float rs = rsqrtf(var + 1e-5f);
        float zv[4];
        bf16x4 pk;
#pragma unroll
        for (int j = 0; j < 4; j++) {
            zv[j] = (v[j] - mu) * rs * lwv[j] + lbv[j];
            pk[j] = (bf16_t)zv[j];
        }
        *reinterpret_cast<bf16x4*>(&zs[(l32 >> 2) * 512 + roff * 16 + (l32 & 3) * 4]) = pk;
        f32x4 pb = {0.f, 0.f, 0.f, 0.f};
#pragma unroll
        for (int j = 0; j < 4; j++)
#pragma unroll
            for (int hh = 0; hh < 4; hh++) pb[hh] += zv[j] * wbj[j][hh];
#pragma unroll
        for (int m = 1; m < 32; m <<= 1) {
#pragma unroll
            for (int hh = 0; hh < 4; hh++) pb[hh] += __shfl_xor(pb[hh], m);
        }
        if (l32 == 0) {
#pragma unroll
            for (int hh = 0; hh < 4; hh++)
                bias_s[hh][roff] = pb[hh] * 1.4426950408889634f;
        }
    }
    __syncthreads();
    if (t < 128) {
        bias3[(size_t)(t >> 5) * NN + rowbase + (t & 31)] = bias_s[t >> 5][t & 31];
    }
    bf16_t* dst = zF + (size_t)blockIdx.x * 4096;
#pragma unroll
    for (int p = 0; p < 2; p++) {
        int c = p * 2048 + t * 8;
        *reinterpret_cast<bf16x8*>(dst + c) = *reinterpret_cast<bf16x8*>(zs + c);
    }
}

// ---------------- bias transpose: bias2[h][k][q] = bias3[h][q*256+k] ----------------
__global__ __launch_bounds__(256) void biastr_kernel(const float* __restrict__ bias3,
                                                     float* __restrict__ bias2) {
    __shared__ float T[64][68];
    int t = threadIdx.x;
    int h = blockIdx.x >> 4;
    int q0 = ((blockIdx.x >> 2) & 3) * 64, k0 = (blockIdx.x & 3) * 64;
#pragma unroll
    for (int i = 0; i < 4; i++) {
        int id = i * 256 + t;
        int r = id >> 4, cb = id & 15;
        f32x4 val = *reinterpret_cast<const f32x4*>(&bias3[h * NN + (q0 + r) * 256 + k0 + cb * 4]);
        *reinterpret_cast<f32x4*>(&T[r][cb * 4]) = val;
    }
    __syncthreads();
#pragma unroll
    for (int i = 0; i < 4; i++) {
        int id = i * 256 + t;
        int kr = id >> 4, qb = id & 15;
        f32x4 o;
#pragma unroll
        for (int j = 0; j < 4; j++) o[j] = T[qb * 4 + j][kr];
        *reinterpret_cast<f32x4*>(&bias2[h * NN + (k0 + kr) * 256 + q0 + qb * 4]) = o;
    }
}

// ---------- fused QKVG projection + flash attention per (b,h), 8-wave blocks ----------
// Projection split into {K,V} -> barrier -> {Q,G}: only 2 f32x16 accumulators live
// per phase (32 regs) -> peak ~110 unified regs -> 4 waves/SIMD (R14 fused-4-acc
// version peaked ~160 -> 2.8 waves/SIMD, occupancy-capped at 35%).
__global__ __launch_bounds__(512, 4) void fat_kernel(const bf16_t* __restrict__ zF,
                                                     const bf16_t* __restrict__ wf,
                                                     const float* __restrict__ bias2,
                                                     bf16_t* __restrict__ om2) {
    __shared__ bf16_t Kh[256][44];   // [key][c] padded -> conflict-free b128
    __shared__ bf16_t Vt[32][268];   // [c][key] padded -> 2-way b64 (free)
    int t = threadIdx.x;
    int id = blockIdx.x;
    int h = (id >> 3) & 3;
    int b = (id & 7) + (id >> 5) * 8;
    int w = t >> 6, lane = t & 63;
    int rsel = lane & 31, hi = lane >> 5;
    int hi8 = hi * 8, hi4 = hi * 4;
    bool lo = (hi == 0);
    const float SCL2 = 0.17677669529663687f * 1.4426950408889634f;  // scale * log2(e)
    const bf16_t* zg0 = zF + (size_t)(b * 8 + w) * 4096;  // this wave's 32-row group
    int fro = rsel * 16 + hi8;
    int qpos = w * 32 + rsel;
    const float* bq = bias2 + (size_t)h * NN + qpos;  // + key*256

    // ---- Phase 1: K,V projection (2 accumulators) -> LDS ----
    {
        const bf16_t* wk = wf + (size_t)(1 * 4 + h) * 4096;
        const bf16_t* wv = wf + (size_t)(2 * 4 + h) * 4096;
        f32x16 ak, av;
#pragma unroll
        for (int i = 0; i < 16; i++) { ak[i] = 0.f; av[i] = 0.f; }
#pragma unroll
        for (int ks = 0; ks < 8; ks++) {
            int off = ks * 512 + fro;
            bf16x8 zb = *reinterpret_cast<const bf16x8*>(zg0 + off);
            bf16x8 fk = *reinterpret_cast<const bf16x8*>(wk + off);
            bf16x8 fv = *reinterpret_cast<const bf16x8*>(wv + off);
            ak = __builtin_amdgcn_mfma_f32_32x32x16_bf16(fk, zb, ak, 0, 0, 0);
            av = __builtin_amdgcn_mfma_f32_32x32x16_bf16(fv, zb, av, 0, 0, 0);
        }
        int key0 = w * 32 + rsel;
        bf16x8 f0, f1;
        packX(ak, lo, f0, f1);
        *reinterpret_cast<bf16x8*>(&Kh[key0][hi8]) = f0;
        *reinterpret_cast<bf16x8*>(&Kh[key0][16 + hi8]) = f1;
#pragma unroll
        for (int r = 0; r < 16; r++) {
            int c = (r & 3) + 8 * (r >> 2) + hi4;
            Vt[c][key0] = (bf16_t)av[r];
        }
    }
    __syncthreads();   // K/V visible; Q/G off the barrier's critical path

    // chunk-0 bias load: overlaps with phase-2 MFMAs
    f32x16 bv;
#pragma unroll
    for (int e = 0; e < 16; e++) {
        int key = 8 * (e >> 2) + hi4 + (e & 3);
        bv[e] = bq[(size_t)key * 256];
    }

    // ---- Phase 2: Q,G projection (2 accumulators) ----
    bf16x8 qf0, qf1;
    f32x16 sg;   // sigmoid(g) kept in-register through attention
    {
        const bf16_t* wq = wf + (size_t)(0 * 4 + h) * 4096;
        const bf16_t* wg = wf + (size_t)(3 * 4 + h) * 4096;
        f32x16 aq, ag;
#pragma unroll
        for (int i = 0; i < 16; i++) { aq[i] = 0.f; ag[i] = 0.f; }
#pragma unroll
        for (int ks = 0; ks < 8; ks++) {
            int off = ks * 512 + fro;
            bf16x8 zb = *reinterpret_cast<const bf16x8*>(zg0 + off);
            bf16x8 fq = *reinterpret_cast<const bf16x8*>(wq + off);
            bf16x8 fg = *reinterpret_cast<const bf16x8*>(wg + off);
            aq = __builtin_amdgcn_mfma_f32_32x32x16_bf16(fq, zb, aq, 0, 0, 0);
            ag = __builtin_amdgcn_mfma_f32_32x32x16_bf16(fg, zb, ag, 0, 0, 0);
        }
#pragma unroll
        for (int i = 0; i < 16; i++) sg[i] = 1.0f / (1.0f + __expf(-ag[i]));
#pragma unroll
        for (int i = 0; i < 16; i++) aq[i] *= SCL2;
        packX(aq, lo, qf0, qf1);
    }

    // ---- flash attention: 32 q-rows per wave; s init = bias (C-layout) ----
    {
        f32x16 of;
#pragma unroll
        for (int i = 0; i < 16; i++) of[i] = 0.f;
        float m = -1e30f, l = 0.f;

#pragma unroll
        for (int kt = 0; kt < 8; kt++) {
            bf16x8 k0 = *reinterpret_cast<bf16x8*>(&Kh[kt * 32 + rsel][hi8]);
            bf16x8 k1 = *reinterpret_cast<bf16x8*>(&Kh[kt * 32 + rsel][16 + hi8]);
            f32x16 s = bv;  // bias as C-init: s = qk*SCL2 + bias after the 2 MFMAs
            __builtin_amdgcn_s_setprio(1);
            s = __builtin_amdgcn_mfma_f32_32x32x16_bf16(k0, qf0, s, 0, 0, 0);
            s = __builtin_amdgcn_mfma_f32_32x32x16_bf16(k1, qf1, s, 0, 0, 0);
            __builtin_amdgcn_s_setprio(0);
            // prefetch next chunk's bias
            if (kt < 7) {
#pragma unroll
                for (int e = 0; e < 16; e++) {
                    int key = (kt + 1) * 32 + 8 * (e >> 2) + hi4 + (e & 3);
                    bv[e] = bq[(size_t)key * 256];
                }
            }
            // row max via max3-friendly triples: 16 -> 6 -> 2 -> 1
            float t0 = fmaxf(fmaxf(s[0], s[1]), s[2]);
            float t1 = fmaxf(fmaxf(s[3], s[4]), s[5]);
            float t2 = fmaxf(fmaxf(s[6], s[7]), s[8]);
            float t3 = fmaxf(fmaxf(s[9], s[10]), s[11]);
            float t4 = fmaxf(fmaxf(s[12], s[13]), s[14]);
            float u0 = fmaxf(fmaxf(t0, t1), s[15]);
            float u1 = fmaxf(fmaxf(t2, t3), t4);
            float pm = fmaxf(u0, u1);
            pm = fmaxf(pm, __shfl_xor(pm, 32));
            // exact defer-max: rescale only if some lane's max grew
            if (__any(pm > m)) {
                float nm = fmaxf(m, pm);
                float al = __builtin_amdgcn_exp2f(m - nm);
                m = nm;
                l *= al;
#pragma unroll
                for (int i = 0; i < 16; i++) of[i] *= al;
            }
            float ts[8];
#pragma unroll
            for (int e = 0; e < 16; e++) s[e] = __builtin_amdgcn_exp2f(s[e] - m);
#pragma unroll
            for (int e = 0; e < 8; e++) ts[e] = s[e] + s[e + 8];
#pragma unroll
            for (int st = 4; st >= 1; st >>= 1)
#pragma unroll
                for (int e = 0; e < st; e++) ts[e] += ts[e + st];
            l += ts[0];
            // P fragments in native C-layout key order (no cross-lane pack)
            bf16x8 pf0 = frag4(pk2(s[0], s[1]), pk2(s[2], s[3]),
                               pk2(s[4], s[5]), pk2(s[6], s[7]));
            bf16x8 pf1 = frag4(pk2(s[8], s[9]), pk2(s[10], s[11]),
                               pk2(s[12], s[13]), pk2(s[14], s[15]));
            // V fragments with the SAME key order: paired b64 reads
            bf16x8 va = cat44(*reinterpret_cast<bf16x4*>(&Vt[rsel][kt * 32 + hi4]),
                              *reinterpret_cast<bf16x4*>(&Vt[rsel][kt * 32 + 8 + hi4]));
            bf16x8 vb = cat44(*reinterpret_cast<bf16x4*>(&Vt[rsel][kt * 32 + 16 + hi4]),
                              *reinterpret_cast<bf16x4*>(&Vt[rsel][kt * 32 + 24 + hi4]));
            __builtin_amdgcn_s_setprio(1);
            of = __builtin_amdgcn_mfma_f32_32x32x16_bf16(va, pf0, of, 0, 0, 0);
            of = __builtin_amdgcn_mfma_f32_32x32x16_bf16(vb, pf1, of, 0, 0, 0);
            __builtin_amdgcn_s_setprio(0);
        }

        l += __shfl_xor(l, 32);
        float linv = 1.0f / l;
        // in-register gating: o * g (same C-layout), then pack+store once
#pragma unroll
        for (int i = 0; i < 16; i++) of[i] = of[i] * linv * sg[i];
        bf16x8 o0, o1;
        packX(of, lo, o0, o1);
        bf16_t* orow = om2 + ((size_t)h * NN + b * 256 + qpos) * 32;
        *reinterpret_cast<bf16x8*>(orow + hi8) = o0;
        *reinterpret_cast<bf16x8*>(orow + 16 + hi8) = o1;
    }
}

// ---------------- final: out = om @ Wo (om pre-gated), fp32 out ----------
__global__ __launch_bounds__(256) void final_kernel(const bf16_t* __restrict__ om2,
                                                    const bf16_t* __restrict__ wfO,
                                                    float* __restrict__ out) {
    __shared__ __align__(16) char smraw[64 * 136 * 2];
    bf16_t(*As)[136] = reinterpret_cast<bf16_t(*)[136]>(smraw);
    float(*Of)[68] = reinterpret_cast<float(*)[68]>(smraw);
    int t = threadIdx.x;
    int rb = blockIdx.x;
#pragma unroll
    for (int i = 0; i < 4; i++) {
        int c = i * 256 + t;
        int r = c >> 4, off = (c & 15) * 8;
        size_t hm = ((size_t)(off >> 5) * NN + rb * 64 + r) * 32 + (off & 31);
        bf16x8 o8 = *reinterpret_cast<const bf16x8*>(&om2[hm]);
        *reinterpret_cast<bf16x8*>(&As[r][off]) = o8;
    }
    __syncthreads();
    int w = t >> 6, lane = t & 63;
    int lx = lane & 15, ly = lane >> 4;
    int m0 = (w >> 1) * 32, n0 = (w & 1) * 32;
    bf16x8 af[2][4];
#pragma unroll
    for (int mt = 0; mt < 2; mt++)
#pragma unroll
        for (int ks = 0; ks < 4; ks++)
            af[mt][ks] = *reinterpret_cast<bf16x8*>(&As[m0 + mt * 16 + lx][ks * 32 + ly * 8]);
    __syncthreads();  // As dead; Of may alias

    for (int half = 0; half < 2; half++) {
        int nc0 = half * 64;
        bf16x8 bfr[2][4];
#pragma unroll
        for (int nt = 0; nt < 2; nt++) {
            int oc = ((nc0 + n0) >> 4) + nt;
#pragma unroll
            for (int ks = 0; ks < 4; ks++)
                bfr[nt][ks] = *reinterpret_cast<const bf16x8*>(
                    &wfO[oc * 2048 + ks * 512 + lx * 32 + ly * 8]);
        }
        f32x4 acc[2][2];
#pragma unroll
        for (int mt = 0; mt < 2; mt++)
#pragma unroll
            for (int nt = 0; nt < 2; nt++) acc[mt][nt] = (f32x4){0.f, 0.f, 0.f, 0.f};
#pragma unroll
        for (int ks = 0; ks < 4; ks++)
#pragma unroll
            for (int mt = 0; mt < 2; mt++)
#pragma unroll
                for (int nt = 0; nt < 2; nt++)
                    acc[mt][nt] = __builtin_amdgcn_mfma_f32_16x16x32_bf16(af[mt][ks], bfr[nt][ks], acc[mt][nt], 0, 0, 0);
#pragma unroll
        for (int mt = 0; mt < 2; mt++)
#pragma unroll
            for (int nt = 0; nt < 2; nt++)
#pragma unroll
                for (int r = 0; r < 4; r++)
                    Of[m0 + mt * 16 + ly * 4 + r][n0 + nt * 16 + lx] = acc[mt][nt][r];
        __syncthreads();
#pragma unroll
        for (int j = 0; j < 4; j++) {
            int ch = j * 256 + t;
            int r = ch >> 4, cb = ch & 15;
            f32x4 val = *reinterpret_cast<f32x4*>(&Of[r][cb * 4]);
            *reinterpret_cast<f32x4*>(&out[(rb * 64 + r) * 128 + nc0 + cb * 4]) = val;
        }
        __syncthreads();
    }
}

extern "C" void kernel_launch(void* const* d_in, const int* in_sizes, int n_in,
                              void* d_out, int out_size, void* d_ws, size_t ws_size,
                              hipStream_t stream) {
    const float* x   = (const float*)d_in[0];
    const float* lnw = (const float*)d_in[1];
    const float* lnb = (const float*)d_in[2];
    const float* Wb  = (const float*)d_in[3];
    const float* Wq  = (const float*)d_in[4];
    const float* Wk  = (const float*)d_in[5];
    const float* Wv  = (const float*)d_in[6];
    const float* Wg  = (const float*)d_in[7];
    const float* Wo  = (const float*)d_in[8];
    float* out = (float*)d_out;

    char* ws = (char*)d_ws;
    const size_t MAT = (size_t)NN * 128 * sizeof(bf16_t);  // 16 MB
    bf16_t* zF    = (bf16_t*)(ws);                           // fragment-ready z
    bf16_t* omat  = (bf16_t*)(ws + MAT);                     // head-major, pre-gated
    bf16_t* wf    = (bf16_t*)(ws + 2 * MAT);                 // 16*4096 bf16 = 128KB
    bf16_t* wfO   = (bf16_t*)(ws + 2 * MAT + (128 << 10));   // 8*2048 bf16 = 32KB
    float*  bias3 = (float*)(ws + 2 * MAT + (1 << 20));      // 1MB
    float*  bias2 = (float*)(ws + 2 * MAT + (2 << 20));      // 1MB

    convw_kernel<<<24, 256, 0, stream>>>(Wq, Wk, Wv, Wg, Wo, wf, wfO);
    ln_kernel<<<2048, 256, 0, stream>>>(x, lnw, lnb, Wb, zF, bias3);
    biastr_kernel<<<64, 256, 0, stream>>>(bias3, bias2);
    fat_kernel<<<1024, 512, 0, stream>>>(zF, wf, bias2, omat);
    final_kernel<<<1024, 256, 0, stream>>>(omat, wfO, out);
}